// Round 11
// baseline (401.833 us; speedup 1.0000x reference)
//
#include <hip/hip_runtime.h>
#include <hip/hip_bf16.h>
#include <stdint.h>

#define LOG2E 1.44269504f
#define NROWS 8192

using bf16x8 = __attribute__((ext_vector_type(8))) short;
using f32x4  = __attribute__((ext_vector_type(4))) float;

__device__ __forceinline__ unsigned short f2bf(float f) {
    unsigned u = __float_as_uint(f);
    u += 0x7fff + ((u >> 16) & 1);          // RNE
    return (unsigned short)(u >> 16);
}
__device__ __forceinline__ unsigned cvt_pk_bf16(float lo, float hi) {
    unsigned r;
    asm("v_cvt_pk_bf16_f32 %0, %1, %2" : "=v"(r) : "v"(lo), "v"(hi));
    return r;
}
__device__ __forceinline__ float fast_exp2(float x) { return __builtin_amdgcn_exp2f(x); }

#define MFMA __builtin_amdgcn_mfma_f32_16x16x32_bf16

// ---------------------------------------------------------------------------
// Setup (round-5 verbatim, VERIFIED) + zeroing of the 768 handoff counters.
// ---------------------------------------------------------------------------
__global__ __launch_bounds__(256) void setup_kernel(
    const float* __restrict__ x, const int* __restrict__ adj, const float* __restrict__ h_prev,
    const float* __restrict__ W0, const float* __restrict__ as0, const float* __restrict__ ad0,
    const float* __restrict__ W1, const float* __restrict__ as1, const float* __restrict__ ad1,
    const float* __restrict__ W2, const float* __restrict__ as2, const float* __restrict__ ad2,
    const float* __restrict__ gwi, const float* __restrict__ gwh,
    const float* __restrict__ Wa1, const float* __restrict__ Wc1,
    unsigned long long* __restrict__ maskbits, unsigned short* __restrict__ xpad,
    unsigned short* __restrict__ hp16,
    unsigned short* __restrict__ W0Tp, unsigned short* __restrict__ W1T, unsigned short* __restrict__ W2T,
    unsigned short* __restrict__ wi16, unsigned short* __restrict__ wh16,
    unsigned short* __restrict__ Wa1T, unsigned short* __restrict__ Wc1T,
    unsigned short* __restrict__ Wsd0, unsigned short* __restrict__ Wsd1, unsigned short* __restrict__ Wsd2,
    int* __restrict__ cnt)
{
    int tid  = blockIdx.x * 256 + threadIdx.x;   // 0 .. 262143
    int lane = threadIdx.x & 63;
    int wv   = tid >> 6;

    if (tid < 768) cnt[tid] = 0;                 // handoff counters (3 layers x 256)

    #pragma unroll
    for (int i = 0; i < 4; ++i) {
        int w   = wv * 4 + i;
        int row = w >> 4, wc = w & 15;
        int j   = wc * 64 + lane;
        unsigned long long m = __ballot(adj[row * 1024 + j] > 0);
        if (lane == 0) maskbits[w] = m;
    }
    {
        int n = tid >> 5, k = tid & 31;
        xpad[tid] = (k < 3) ? f2bf(x[n * 3 + k]) : (unsigned short)0;
    }
    hp16[tid]          = f2bf(h_prev[tid]);
    hp16[tid + 262144] = f2bf(h_prev[tid + 262144]);
    if (tid < 12288) {
        int n = tid >> 6, k = tid & 63;
        W1T[tid]  = f2bf(W1[k * 192 + n]);
        W2T[tid]  = f2bf(W2[k * 192 + n]);
        wi16[tid] = f2bf(gwi[tid]);
        wh16[tid] = f2bf(gwh[tid]);
    }
    if (tid < 6144) {
        int n = tid >> 5, k = tid & 31;
        W0Tp[tid] = (k < 3) ? f2bf(W0[k * 192 + n]) : (unsigned short)0;
    }
    if (tid < 2048) {
        int n = tid >> 6, k = tid & 63;
        Wa1T[tid] = f2bf(Wa1[k * 32 + n]);
        Wc1T[tid] = f2bf(Wc1[k * 32 + n]);
    }
    if (tid < 16 * 32) {
        int c = tid >> 5, k = tid & 31;
        float v = 0.f;
        if (c < 6 && k < 3) {
            int h = c >> 1; const float* a = (c & 1) ? ad0 : as0;
            for (int f = 0; f < 64; ++f) v += W0[k * 192 + h * 64 + f] * a[h * 64 + f];
        }
        Wsd0[tid] = f2bf(v);
    }
    if (tid < 16 * 64) {
        int c = tid >> 6, k = tid & 63;
        float v1 = 0.f, v2 = 0.f;
        if (c < 6) {
            int h = c >> 1;
            const float* a1 = (c & 1) ? ad1 : as1;
            const float* a2 = (c & 1) ? ad2 : as2;
            for (int f = 0; f < 64; ++f) {
                v1 += W1[k * 192 + h * 64 + f] * a1[h * 64 + f];
                v2 += W2[k * 192 + h * 64 + f] * a2[h * 64 + f];
            }
        }
        Wsd1[tid] = f2bf(v1);
        Wsd2[tid] = f2bf(v2);
    }
}

// ---------------------------------------------------------------------------
// proj0 (round-5 proj_kernel<32,0> verbatim, VERIFIED). Grid 512 x 256.
// ---------------------------------------------------------------------------
__global__ __launch_bounds__(256) void proj0_kernel(
    const unsigned short* __restrict__ A16,
    const unsigned short* __restrict__ WT,    // [192][32]
    const unsigned short* __restrict__ WsdT,  // [16][32]
    unsigned short* __restrict__ VT,
    float* __restrict__ st, float* __restrict__ dt)
{
    constexpr int KDIM = 32;
    int b     = blockIdx.x & 7;
    int nbase = (int)(blockIdx.x >> 3) << 4;
    int fg = threadIdx.x >> 6, l = threadIdx.x & 63;
    int l15 = l & 15, l4 = l >> 4;
    int row = b * 1024 + nbase + l15;

    bf16x8 afr = *(const bf16x8*)(A16 + (size_t)row * KDIM + l4 * 8);

    f32x4 acc[3] = {(f32x4)0.f, (f32x4)0.f, (f32x4)0.f};
    f32x4 sdacc  = (f32x4)0.f;
    {
        int k = l4 * 8;
        #pragma unroll
        for (int t = 0; t < 3; ++t) {
            int n = (fg * 3 + t) * 16 + l15;
            bf16x8 bf = *(const bf16x8*)(WT + (size_t)n * KDIM + k);
            acc[t] = MFMA(afr, bf, acc[t], 0, 0, 0);
        }
        if (fg == 0) {
            bf16x8 bsd = *(const bf16x8*)(WsdT + (size_t)l15 * KDIM + k);
            sdacc = MFMA(afr, bsd, sdacc, 0, 0, 0);
        }
    }
    #pragma unroll
    for (int t = 0; t < 3; ++t) {
        int hf = (fg * 3 + t) * 16 + l15;
        size_t base = ((size_t)(b * 3 + (hf >> 6)) * 64 + (hf & 63)) * 1024 + nbase + l4 * 4;
        uint2 pk;
        pk.x = cvt_pk_bf16(acc[t][0], acc[t][1]);
        pk.y = cvt_pk_bf16(acc[t][2], acc[t][3]);
        *(uint2*)(VT + base) = pk;
    }
    if (fg == 0 && l15 < 6) {
        int h = l15 >> 1;
        float* dst = (l15 & 1) ? dt : st;
        size_t base = (size_t)(b * 3 + h) * 1024 + nbase + l4 * 4;
        #pragma unroll
        for (int r = 0; r < 4; ++r) dst[base + r] = sdacc[r];
    }
}

// ---------------------------------------------------------------------------
// attn_fused<NEXT>: round-5 attn verbatim (grid 768 XCD-swizzled, 4 waves,
// 32-row tile, j-split) -> hacc. Then the LAST of the 3 head-blocks of each
// (b,tile) (device-scope atomic counter + fences) executes the follow-on:
//   NEXT==1: proj layer1, rsum := sf          (round-5 proj MODE1, 32-row)
//   NEXT==2: proj layer2, sf += rsum, rsum := sf (MODE2)
//   NEXT==3: GRU + actor/critic heads          (round-5 gruheads body)
// Winner identity varies; computed values do not -> deterministic output.
// ---------------------------------------------------------------------------
template<int NEXT>
__global__ __launch_bounds__(256) void attn_fused(
    const unsigned short* __restrict__ VTin,
    const float* __restrict__ stin, const float* __restrict__ dtin,
    const unsigned int* __restrict__ maskw,
    float* __restrict__ hacc,
    int* __restrict__ cnt,                    // [256] per-layer
    const unsigned short* __restrict__ WT, const unsigned short* __restrict__ WsdT,
    float* __restrict__ rsum,
    unsigned short* __restrict__ VTout, float* __restrict__ stout, float* __restrict__ dtout,
    const unsigned short* __restrict__ hp16,
    const unsigned short* __restrict__ wi16, const unsigned short* __restrict__ wh16,
    const float* __restrict__ bi, const float* __restrict__ bh_,
    const float* __restrict__ hprev,
    const unsigned short* __restrict__ Wa1T, const unsigned short* __restrict__ Wc1T,
    const float* __restrict__ ba1, const float* __restrict__ Wa2, const float* __restrict__ ba2,
    const float* __restrict__ bc1, const float* __restrict__ Wc2, const float* __restrict__ bc2,
    float* __restrict__ hnew, float* __restrict__ probs, float* __restrict__ value)
{
    __shared__ float F1lds[1024];
    __shared__ float F2lds[1024];
    __shared__ unsigned int lmask[32 * 33];
    __shared__ float pO[4][32 * 68];
    __shared__ float pZ[4][32];
    __shared__ int s_done;
    __shared__ unsigned short hnlds[(NEXT == 3) ? 32 * 72 : 2];

    int b     = blockIdx.x & 7;               // = XCD
    int q     = blockIdx.x >> 3;              // 0..95
    int h     = q >> 5;
    int bh    = b * 3 + h;
    int ibase = (q & 31) << 5;
    int w = threadIdx.x >> 6, l = threadIdx.x & 63;
    int l15 = l & 15, l4 = l >> 4;

    #pragma unroll
    for (int i = 0; i < 4; ++i) {
        int idx = threadIdx.x + i * 256;
        int row = idx >> 5, wd = idx & 31;
        lmask[row * 33 + wd] = maskw[(size_t)(ibase + row) * 32 + wd];
    }
    {
        int t4 = threadIdx.x * 4;
        float4 dv4 = *(const float4*)(dtin + (size_t)bh * 1024 + t4);
        *(float4*)(F1lds + t4) = make_float4(
            fast_exp2(dv4.x * LOG2E), fast_exp2(dv4.y * LOG2E),
            fast_exp2(dv4.z * LOG2E), fast_exp2(dv4.w * LOG2E));
        *(float4*)(F2lds + t4) = make_float4(
            fast_exp2(dv4.x * (0.2f * LOG2E)), fast_exp2(dv4.y * (0.2f * LOG2E)),
            fast_exp2(dv4.z * (0.2f * LOG2E)), fast_exp2(dv4.w * (0.2f * LOG2E)));
    }
    __syncthreads();

    float R0 = fast_exp2(stin[(size_t)bh * 1024 + ibase + l15]      * (-0.8f * LOG2E));
    float R1 = fast_exp2(stin[(size_t)bh * 1024 + ibase + 16 + l15] * (-0.8f * LOG2E));
    const unsigned short* vbase = VTin + (size_t)bh * 64 * 1024;

    f32x4 acc[2][4];
    #pragma unroll
    for (int rg = 0; rg < 2; ++rg)
        #pragma unroll
        for (int f4 = 0; f4 < 4; ++f4) acc[rg][f4] = (f32x4)0.f;
    float z0 = 0.f, z1 = 0.f;
    int jb = w * 256;
    int w8 = w * 8;

    auto ldstep = [&](int it, float4& F1a, float4& F1b, float4& F2a, float4& F2b,
                      bf16x8& Va, bf16x8& Vb, bf16x8& Vc, bf16x8& Vd) {
        int kk = jb + it * 32 + l4 * 8;
        F1a = *(const float4*)(F1lds + kk);
        F1b = *(const float4*)(F1lds + kk + 4);
        F2a = *(const float4*)(F2lds + kk);
        F2b = *(const float4*)(F2lds + kk + 4);
        Va = *(const bf16x8*)(vbase + (size_t)(l15)      * 1024 + kk);
        Vb = *(const bf16x8*)(vbase + (size_t)(16 + l15) * 1024 + kk);
        Vc = *(const bf16x8*)(vbase + (size_t)(32 + l15) * 1024 + kk);
        Vd = *(const bf16x8*)(vbase + (size_t)(48 + l15) * 1024 + kk);
    };
    auto cstep = [&](int it, float4 F1a, float4 F1b, float4 F2a, float4 F2b,
                     bf16x8 Va, bf16x8 Vb, bf16x8 Vc, bf16x8 Vd) {
        unsigned m0 = (lmask[l15 * 33 + w8 + it]        >> (l4 * 8)) & 0xffu;
        unsigned m1 = (lmask[(16 + l15) * 33 + w8 + it] >> (l4 * 8)) & 0xffu;
        float f1[8] = {F1a.x, F1a.y, F1a.z, F1a.w, F1b.x, F1b.y, F1b.z, F1b.w};
        float f2[8] = {F2a.x, F2a.y, F2a.z, F2a.w, F2b.x, F2b.y, F2b.z, F2b.w};
        float p0[8], p1[8];
        #pragma unroll
        for (int j = 0; j < 8; ++j) {
            float a0 = fmaxf(f1[j], R0 * f2[j]);
            p0[j] = ((m0 >> j) & 1) ? a0 : 0.f;
            z0 += p0[j];
            float a1 = fmaxf(f1[j], R1 * f2[j]);
            p1[j] = ((m1 >> j) & 1) ? a1 : 0.f;
            z1 += p1[j];
        }
        union { unsigned u[4]; bf16x8 v; } ua, ub;
        #pragma unroll
        for (int jj = 0; jj < 4; ++jj) {
            ua.u[jj] = cvt_pk_bf16(p0[2 * jj], p0[2 * jj + 1]);
            ub.u[jj] = cvt_pk_bf16(p1[2 * jj], p1[2 * jj + 1]);
        }
        acc[0][0] = MFMA(ua.v, Va, acc[0][0], 0, 0, 0);
        acc[0][1] = MFMA(ua.v, Vb, acc[0][1], 0, 0, 0);
        acc[0][2] = MFMA(ua.v, Vc, acc[0][2], 0, 0, 0);
        acc[0][3] = MFMA(ua.v, Vd, acc[0][3], 0, 0, 0);
        acc[1][0] = MFMA(ub.v, Va, acc[1][0], 0, 0, 0);
        acc[1][1] = MFMA(ub.v, Vb, acc[1][1], 0, 0, 0);
        acc[1][2] = MFMA(ub.v, Vc, acc[1][2], 0, 0, 0);
        acc[1][3] = MFMA(ub.v, Vd, acc[1][3], 0, 0, 0);
    };

    float4 F1a0, F1b0, F2a0, F2b0, F1a1, F1b1, F2a1, F2b1;
    bf16x8 Va0, Vb0, Vc0, Vd0, Va1, Vb1, Vc1, Vd1;
    ldstep(0, F1a0, F1b0, F2a0, F2b0, Va0, Vb0, Vc0, Vd0);
    #pragma unroll
    for (int it = 0; it < 8; it += 2) {
        if (it + 1 < 8) ldstep(it + 1, F1a1, F1b1, F2a1, F2b1, Va1, Vb1, Vc1, Vd1);
        cstep(it, F1a0, F1b0, F2a0, F2b0, Va0, Vb0, Vc0, Vd0);
        if (it + 2 < 8) ldstep(it + 2, F1a0, F1b0, F2a0, F2b0, Va0, Vb0, Vc0, Vd0);
        if (it + 1 < 8) cstep(it + 1, F1a1, F1b1, F2a1, F2b1, Va1, Vb1, Vc1, Vd1);
    }

    z0 += __shfl_xor(z0, 16); z0 += __shfl_xor(z0, 32);
    z1 += __shfl_xor(z1, 16); z1 += __shfl_xor(z1, 32);
    if (l4 == 0) pZ[w][l15] = z0;
    if (l4 == 1) pZ[w][16 + l15] = z1;
    #pragma unroll
    for (int rg = 0; rg < 2; ++rg)
        #pragma unroll
        for (int f4 = 0; f4 < 4; ++f4)
            #pragma unroll
            for (int r = 0; r < 4; ++r)
                pO[w][(rg * 16 + l4 * 4 + r) * 68 + f4 * 16 + l15] = acc[rg][f4][r];
    __syncthreads();

    {
        int row = threadIdx.x >> 3;
        int fo  = (threadIdx.x & 7) * 8;
        float zs = pZ[0][row] + pZ[1][row] + pZ[2][row] + pZ[3][row];
        float rcp = 1.f / ((zs == 0.f) ? 1.f : zs);
        float o[8] = {0.f,0.f,0.f,0.f,0.f,0.f,0.f,0.f};
        #pragma unroll
        for (int ww = 0; ww < 4; ++ww) {
            const float* pp = &pO[ww][row * 68 + fo];
            float4 a = *(const float4*)(pp);
            float4 c = *(const float4*)(pp + 4);
            o[0] += a.x; o[1] += a.y; o[2] += a.z; o[3] += a.w;
            o[4] += c.x; o[5] += c.y; o[6] += c.z; o[7] += c.w;
        }
        float* op = hacc + (size_t)(b * 1024 + ibase + row) * 192 + h * 64 + fo;
        *(float4*)(op)     = make_float4(o[0] * rcp, o[1] * rcp, o[2] * rcp, o[3] * rcp);
        *(float4*)(op + 4) = make_float4(o[4] * rcp, o[5] * rcp, o[6] * rcp, o[7] * rcp);
    }

    // ---- handoff: last of the 3 head-blocks of (b,tile) continues ----
    __threadfence();                              // release this block's hacc
    __syncthreads();
    if (threadIdx.x == 0)
        s_done = atomicAdd(&cnt[b * 32 + (q & 31)], 1);
    __syncthreads();
    if (s_done != 2) return;
    __threadfence();                              // acquire other blocks' hacc

    int nb = ibase;                               // 32-row tile base
    int rh = w & 1, fg = w >> 1;
    int arow = b * 1024 + nb + rh * 16 + l15;

    if constexpr (NEXT == 1 || NEXT == 2) {
        float sf[2][8];
        #pragma unroll
        for (int ks = 0; ks < 2; ++ks) {
            int fb = ks * 32 + l4 * 8;
            const float* hp = hacc + (size_t)arow * 192 + fb;
            float4 a0 = *(const float4*)(hp);       float4 a1 = *(const float4*)(hp + 4);
            float4 c0 = *(const float4*)(hp + 64);  float4 c1 = *(const float4*)(hp + 68);
            float4 e0 = *(const float4*)(hp + 128); float4 e1 = *(const float4*)(hp + 132);
            float m[8] = {a0.x + c0.x + e0.x, a0.y + c0.y + e0.y, a0.z + c0.z + e0.z, a0.w + c0.w + e0.w,
                          a1.x + c1.x + e1.x, a1.y + c1.y + e1.y, a1.z + c1.z + e1.z, a1.w + c1.w + e1.w};
            float r[8] = {0.f,0.f,0.f,0.f,0.f,0.f,0.f,0.f};
            if constexpr (NEXT == 2) {
                const float* rp = rsum + (size_t)arow * 64 + fb;
                float4 r0 = *(const float4*)(rp); float4 r1 = *(const float4*)(rp + 4);
                r[0]=r0.x; r[1]=r0.y; r[2]=r0.z; r[3]=r0.w;
                r[4]=r1.x; r[5]=r1.y; r[6]=r1.z; r[7]=r1.w;
            }
            #pragma unroll
            for (int j = 0; j < 8; ++j) {
                float v = m[j] * (1.f / 3.f);
                v = (v > 0.f) ? v : (fast_exp2(v * LOG2E) - 1.f);
                sf[ks][j] = v + r[j];
            }
        }
        __syncthreads();                  // rsum reads done before writes
        if (fg == 0) {                    // waves 0,1 cover rh 0,1
            #pragma unroll
            for (int ks = 0; ks < 2; ++ks) {
                float* rp = rsum + (size_t)arow * 64 + ks * 32 + l4 * 8;
                *(float4*)(rp)     = make_float4(sf[ks][0], sf[ks][1], sf[ks][2], sf[ks][3]);
                *(float4*)(rp + 4) = make_float4(sf[ks][4], sf[ks][5], sf[ks][6], sf[ks][7]);
            }
        }
        bf16x8 afr[2];
        #pragma unroll
        for (int ks = 0; ks < 2; ++ks) {
            union { unsigned u[4]; bf16x8 v; } uu;
            #pragma unroll
            for (int jj = 0; jj < 4; ++jj)
                uu.u[jj] = cvt_pk_bf16(sf[ks][2 * jj], sf[ks][2 * jj + 1]);
            afr[ks] = uu.v;
        }
        f32x4 pc[6] = {(f32x4)0.f, (f32x4)0.f, (f32x4)0.f, (f32x4)0.f, (f32x4)0.f, (f32x4)0.f};
        f32x4 sdacc = (f32x4)0.f;
        #pragma unroll
        for (int ks = 0; ks < 2; ++ks) {
            int k = ks * 32 + l4 * 8;
            #pragma unroll
            for (int t = 0; t < 6; ++t) {
                int n = (fg * 6 + t) * 16 + l15;
                bf16x8 bf = *(const bf16x8*)(WT + (size_t)n * 64 + k);
                pc[t] = MFMA(afr[ks], bf, pc[t], 0, 0, 0);
            }
            if (fg == 0) {
                bf16x8 bs = *(const bf16x8*)(WsdT + (size_t)l15 * 64 + k);
                sdacc = MFMA(afr[ks], bs, sdacc, 0, 0, 0);
            }
        }
        #pragma unroll
        for (int t = 0; t < 6; ++t) {
            int hf = (fg * 6 + t) * 16 + l15;
            size_t base = ((size_t)(b * 3 + (hf >> 6)) * 64 + (hf & 63)) * 1024 + nb + rh * 16 + l4 * 4;
            uint2 pk;
            pk.x = cvt_pk_bf16(pc[t][0], pc[t][1]);
            pk.y = cvt_pk_bf16(pc[t][2], pc[t][3]);
            *(uint2*)(VTout + base) = pk;
        }
        if (fg == 0 && l15 < 6) {
            int hh = l15 >> 1;
            float* dstp = (l15 & 1) ? dtout : stout;
            size_t base = (size_t)(b * 3 + hh) * 1024 + nb + rh * 16 + l4 * 4;
            #pragma unroll
            for (int r = 0; r < 4; ++r) dstp[base + r] = sdacc[r];
        }
    } else {
        // ---- NEXT == 3: GRU + heads (round-5 gruheads body, nbase = nb) ----
        int g2 = w >> 1;
        bf16x8 ai[2];
        #pragma unroll
        for (int ks = 0; ks < 2; ++ks) {
            int fb = ks * 32 + l4 * 8;
            const float* hp = hacc + (size_t)arow * 192 + fb;
            float4 a0 = *(const float4*)(hp);       float4 a1 = *(const float4*)(hp + 4);
            float4 c0 = *(const float4*)(hp + 64);  float4 c1 = *(const float4*)(hp + 68);
            float4 e0 = *(const float4*)(hp + 128); float4 e1 = *(const float4*)(hp + 132);
            const float* rp = rsum + (size_t)arow * 64 + fb;
            float4 r0 = *(const float4*)(rp);       float4 r1 = *(const float4*)(rp + 4);
            float m[8] = {a0.x + c0.x + e0.x, a0.y + c0.y + e0.y, a0.z + c0.z + e0.z, a0.w + c0.w + e0.w,
                          a1.x + c1.x + e1.x, a1.y + c1.y + e1.y, a1.z + c1.z + e1.z, a1.w + c1.w + e1.w};
            float rr[8] = {r0.x, r0.y, r0.z, r0.w, r1.x, r1.y, r1.z, r1.w};
            float sf[8];
            #pragma unroll
            for (int j = 0; j < 8; ++j) {
                float v = m[j] * (1.f / 3.f);
                v = (v > 0.f) ? v : (fast_exp2(v * LOG2E) - 1.f);
                sf[j] = v + rr[j];
            }
            union { unsigned u[4]; bf16x8 v; } uu;
            #pragma unroll
            for (int jj = 0; jj < 4; ++jj)
                uu.u[jj] = cvt_pk_bf16(sf[2 * jj], sf[2 * jj + 1]);
            ai[ks] = uu.v;
        }

        f32x4 gi[2][3], gh[2][3];
        #pragma unroll
        for (int t = 0; t < 2; ++t)
            #pragma unroll
            for (int q2 = 0; q2 < 3; ++q2) { gi[t][q2] = (f32x4)0.f; gh[t][q2] = (f32x4)0.f; }

        #pragma unroll
        for (int ks = 0; ks < 2; ++ks) {
            int k = ks * 32 + l4 * 8;
            bf16x8 ah = *(const bf16x8*)(hp16 + (size_t)arow * 64 + k);
            #pragma unroll
            for (int t = 0; t < 2; ++t) {
                #pragma unroll
                for (int q2 = 0; q2 < 3; ++q2) {
                    int n = (q2 * 4 + g2 * 2 + t) * 16 + l15;
                    bf16x8 bwi = *(const bf16x8*)(wi16 + (size_t)n * 64 + k);
                    bf16x8 bwh = *(const bf16x8*)(wh16 + (size_t)n * 64 + k);
                    gi[t][q2] = MFMA(ai[ks], bwi, gi[t][q2], 0, 0, 0);
                    gh[t][q2] = MFMA(ah,     bwh, gh[t][q2], 0, 0, 0);
                }
            }
        }
        #pragma unroll
        for (int t = 0; t < 2; ++t) {
            int c = (g2 * 2 + t) * 16 + l15;
            float bir = bi[c], biz = bi[64 + c], bin = bi[128 + c];
            float bhr = bh_[c], bhz = bh_[64 + c], bhn = bh_[128 + c];
            #pragma unroll
            for (int r = 0; r < 4; ++r) {
                int rloc = rh * 16 + 4 * l4 + r;
                int row = b * 1024 + nb + rloc;
                float rr = (gi[t][0][r] + bir) + (gh[t][0][r] + bhr);
                float zz = (gi[t][1][r] + biz) + (gh[t][1][r] + bhz);
                float rg = 1.f / (1.f + fast_exp2(-rr * LOG2E));
                float zg = 1.f / (1.f + fast_exp2(-zz * LOG2E));
                float narg = (gi[t][2][r] + bin) + rg * (gh[t][2][r] + bhn);
                narg = fminf(fmaxf(narg, -15.f), 15.f);
                float e2 = fast_exp2(2.f * narg * LOG2E);
                float ng = (e2 - 1.f) / (e2 + 1.f);
                float hp = hprev[(size_t)row * 64 + c];
                float hv = (1.f - zg) * ng + zg * hp;
                hnew[(size_t)row * 64 + c] = hv;
                hnlds[rloc * 72 + c] = f2bf(hv);
            }
        }
        __syncthreads();

        const unsigned short* WTh = g2 ? Wc1T : Wa1T;
        f32x4 ach[2] = {(f32x4)0.f, (f32x4)0.f};
        #pragma unroll
        for (int ks = 0; ks < 2; ++ks) {
            int k = ks * 32 + l4 * 8;
            bf16x8 a = *(const bf16x8*)(&hnlds[(rh * 16 + l15) * 72 + k]);
            #pragma unroll
            for (int t = 0; t < 2; ++t) {
                bf16x8 bf = *(const bf16x8*)(WTh + (size_t)(t * 16 + l15) * 64 + k);
                ach[t] = MFMA(a, bf, ach[t], 0, 0, 0);
            }
        }
        int rowbase2 = b * 1024 + nb + rh * 16;
        if (g2 == 0) {
            float p0[4] = {0.f,0.f,0.f,0.f}, p1[4] = {0.f,0.f,0.f,0.f};
            #pragma unroll
            for (int t = 0; t < 2; ++t) {
                int c = t * 16 + l15;
                float b1 = ba1[c], w20 = Wa2[c * 2], w21 = Wa2[c * 2 + 1];
                #pragma unroll
                for (int r = 0; r < 4; ++r) {
                    float v = fmaxf(ach[t][r] + b1, 0.f);
                    p0[r] += v * w20; p1[r] += v * w21;
                }
            }
            #pragma unroll
            for (int r = 0; r < 4; ++r) {
                #pragma unroll
                for (int off = 1; off < 16; off <<= 1) {
                    p0[r] += __shfl_xor(p0[r], off);
                    p1[r] += __shfl_xor(p1[r], off);
                }
                float l0 = p0[r] + ba2[0], l1 = p1[r] + ba2[1];
                float mm = fmaxf(l0, l1);
                float e0 = fast_exp2((l0 - mm) * LOG2E);
                float e1 = fast_exp2((l1 - mm) * LOG2E);
                float s = 1.f / (e0 + e1);
                if (l15 == 0) {
                    int row = rowbase2 + 4 * l4 + r;
                    probs[(size_t)row * 2]     = e0 * s;
                    probs[(size_t)row * 2 + 1] = e1 * s;
                }
            }
        } else {
            float pv[4] = {0.f,0.f,0.f,0.f};
            #pragma unroll
            for (int t = 0; t < 2; ++t) {
                int c = t * 16 + l15;
                float b1 = bc1[c], w2 = Wc2[c];
                #pragma unroll
                for (int r = 0; r < 4; ++r) {
                    float v = fmaxf(ach[t][r] + b1, 0.f);
                    pv[r] += v * w2;
                }
            }
            #pragma unroll
            for (int r = 0; r < 4; ++r) {
                #pragma unroll
                for (int off = 1; off < 16; off <<= 1) pv[r] += __shfl_xor(pv[r], off);
                if (l15 == 0) {
                    int row = rowbase2 + 4 * l4 + r;
                    value[row] = pv[r] + bc2[0];
                }
            }
        }
    }
}

// ---------------------------------------------------------------------------
extern "C" void kernel_launch(void* const* d_in, const int* in_sizes, int n_in,
                              void* d_out, int out_size, void* d_ws, size_t ws_size,
                              hipStream_t stream)
{
    const float* x      = (const float*)d_in[0];
    const int*   adj    = (const int*)d_in[1];
    const float* h_prev = (const float*)d_in[2];
    const float* W0  = (const float*)d_in[3];
    const float* as0 = (const float*)d_in[4];
    const float* ad0 = (const float*)d_in[5];
    const float* W1  = (const float*)d_in[6];
    const float* as1 = (const float*)d_in[7];
    const float* ad1 = (const float*)d_in[8];
    const float* W2  = (const float*)d_in[9];
    const float* as2 = (const float*)d_in[10];
    const float* ad2 = (const float*)d_in[11];
    const float* gwi = (const float*)d_in[12];
    const float* gwh = (const float*)d_in[13];
    const float* gbi = (const float*)d_in[14];
    const float* gbh = (const float*)d_in[15];
    const float* Wa1 = (const float*)d_in[16];
    const float* ba1 = (const float*)d_in[17];
    const float* Wa2 = (const float*)d_in[18];
    const float* ba2 = (const float*)d_in[19];
    const float* Wc1 = (const float*)d_in[20];
    const float* bc1 = (const float*)d_in[21];
    const float* Wc2 = (const float*)d_in[22];
    const float* bc2 = (const float*)d_in[23];

    float* out   = (float*)d_out;
    float* probs = out;            // (8,1024,2)
    float* value = out + 16384;    // (8,1024,1)
    float* hnew  = out + 24576;    // (8,1024,64)

    char* p = (char*)d_ws;
    auto alloc = [&](size_t bytes) { char* q = p; p += (bytes + 255) & ~(size_t)255; return q; };
    auto*  maskb = (unsigned long long*)alloc(16384 * 8);
    auto*  xpad  = (unsigned short*)alloc((size_t)NROWS * 32 * 2);
    auto*  hp16  = (unsigned short*)alloc((size_t)NROWS * 64 * 2);
    auto*  VT_A  = (unsigned short*)alloc((size_t)8 * 3 * 64 * 1024 * 2);
    auto*  VT_B  = (unsigned short*)alloc((size_t)8 * 3 * 64 * 1024 * 2);
    float* stA   = (float*)alloc((size_t)24576 * 4);
    float* dtA   = (float*)alloc((size_t)24576 * 4);
    float* stB   = (float*)alloc((size_t)24576 * 4);
    float* dtB   = (float*)alloc((size_t)24576 * 4);
    float* hacc  = (float*)alloc((size_t)8 * 1024 * 192 * 4);
    float* rsum  = (float*)alloc((size_t)NROWS * 64 * 4);
    auto*  W0Tp  = (unsigned short*)alloc(192 * 32 * 2);
    auto*  W1T   = (unsigned short*)alloc(192 * 64 * 2);
    auto*  W2T   = (unsigned short*)alloc(192 * 64 * 2);
    auto*  wi16  = (unsigned short*)alloc(192 * 64 * 2);
    auto*  wh16  = (unsigned short*)alloc(192 * 64 * 2);
    auto*  Wa1T  = (unsigned short*)alloc(32 * 64 * 2);
    auto*  Wc1T  = (unsigned short*)alloc(32 * 64 * 2);
    auto*  Wsd0  = (unsigned short*)alloc(16 * 32 * 2);
    auto*  Wsd1  = (unsigned short*)alloc(16 * 64 * 2);
    auto*  Wsd2  = (unsigned short*)alloc(16 * 64 * 2);
    int*   cnt   = (int*)alloc(768 * 4);
    (void)ws_size; (void)in_sizes; (void)n_in; (void)out_size;

    const unsigned int* maskw = (const unsigned int*)maskb;

    setup_kernel<<<1024, 256, 0, stream>>>(
        x, adj, h_prev, W0, as0, ad0, W1, as1, ad1, W2, as2, ad2,
        gwi, gwh, Wa1, Wc1,
        maskb, xpad, hp16, W0Tp, W1T, W2T, wi16, wh16, Wa1T, Wc1T,
        Wsd0, Wsd1, Wsd2, cnt);

    proj0_kernel<<<512, 256, 0, stream>>>(xpad, W0Tp, Wsd0, VT_A, stA, dtA);

    // layer0 attn + (last-finisher) proj1
    attn_fused<1><<<768, 256, 0, stream>>>(
        VT_A, stA, dtA, maskw, hacc, cnt,
        W1T, Wsd1, rsum, VT_B, stB, dtB,
        nullptr, nullptr, nullptr, nullptr, nullptr, nullptr,
        nullptr, nullptr, nullptr, nullptr, nullptr, nullptr, nullptr, nullptr,
        nullptr, nullptr, nullptr);

    // layer1 attn + (last-finisher) proj2
    attn_fused<2><<<768, 256, 0, stream>>>(
        VT_B, stB, dtB, maskw, hacc, cnt + 256,
        W2T, Wsd2, rsum, VT_A, stA, dtA,
        nullptr, nullptr, nullptr, nullptr, nullptr, nullptr,
        nullptr, nullptr, nullptr, nullptr, nullptr, nullptr, nullptr, nullptr,
        nullptr, nullptr, nullptr);

    // layer2 attn + (last-finisher) GRU + heads
    attn_fused<3><<<768, 256, 0, stream>>>(
        VT_A, stA, dtA, maskw, hacc, cnt + 512,
        nullptr, nullptr, rsum, nullptr, nullptr, nullptr,
        hp16, wi16, wh16, gbi, gbh, h_prev,
        Wa1T, Wc1T, ba1, Wa2, ba2, bc1, Wc2, bc2,
        hnew, probs, value);
}

// Round 12
// 112.568 us; speedup vs baseline: 3.5697x; 3.5697x over previous
//
#include <hip/hip_runtime.h>
#include <hip/hip_bf16.h>
#include <stdint.h>

#define LOG2E 1.44269504f
#define NROWS 8192

using bf16x8 = __attribute__((ext_vector_type(8))) short;
using f32x4  = __attribute__((ext_vector_type(4))) float;

__device__ __forceinline__ unsigned short f2bf(float f) {
    unsigned u = __float_as_uint(f);
    u += 0x7fff + ((u >> 16) & 1);          // RNE
    return (unsigned short)(u >> 16);
}
__device__ __forceinline__ unsigned cvt_pk_bf16(float lo, float hi) {
    unsigned r;
    asm("v_cvt_pk_bf16_f32 %0, %1, %2" : "=v"(r) : "v"(lo), "v"(hi));
    return r;
}
__device__ __forceinline__ float fast_exp2(float x) { return __builtin_amdgcn_exp2f(x); }

#define MFMA __builtin_amdgcn_mfma_f32_16x16x32_bf16

// ---------------------------------------------------------------------------
// Setup (round-5 verbatim, VERIFIED). Grid 1024 x 256.
// ---------------------------------------------------------------------------
__global__ __launch_bounds__(256) void setup_kernel(
    const float* __restrict__ x, const int* __restrict__ adj, const float* __restrict__ h_prev,
    const float* __restrict__ W0, const float* __restrict__ as0, const float* __restrict__ ad0,
    const float* __restrict__ W1, const float* __restrict__ as1, const float* __restrict__ ad1,
    const float* __restrict__ W2, const float* __restrict__ as2, const float* __restrict__ ad2,
    const float* __restrict__ gwi, const float* __restrict__ gwh,
    const float* __restrict__ Wa1, const float* __restrict__ Wc1,
    unsigned long long* __restrict__ maskbits, unsigned short* __restrict__ xpad,
    unsigned short* __restrict__ hp16,
    unsigned short* __restrict__ W0Tp, unsigned short* __restrict__ W1T, unsigned short* __restrict__ W2T,
    unsigned short* __restrict__ wi16, unsigned short* __restrict__ wh16,
    unsigned short* __restrict__ Wa1T, unsigned short* __restrict__ Wc1T,
    unsigned short* __restrict__ Wsd0, unsigned short* __restrict__ Wsd1, unsigned short* __restrict__ Wsd2)
{
    int tid  = blockIdx.x * 256 + threadIdx.x;   // 0 .. 262143
    int lane = threadIdx.x & 63;
    int wv   = tid >> 6;

    #pragma unroll
    for (int i = 0; i < 4; ++i) {
        int w   = wv * 4 + i;
        int row = w >> 4, wc = w & 15;
        int j   = wc * 64 + lane;
        unsigned long long m = __ballot(adj[row * 1024 + j] > 0);
        if (lane == 0) maskbits[w] = m;
    }
    {
        int n = tid >> 5, k = tid & 31;
        xpad[tid] = (k < 3) ? f2bf(x[n * 3 + k]) : (unsigned short)0;
    }
    hp16[tid]          = f2bf(h_prev[tid]);
    hp16[tid + 262144] = f2bf(h_prev[tid + 262144]);
    if (tid < 12288) {
        int n = tid >> 6, k = tid & 63;
        W1T[tid]  = f2bf(W1[k * 192 + n]);
        W2T[tid]  = f2bf(W2[k * 192 + n]);
        wi16[tid] = f2bf(gwi[tid]);
        wh16[tid] = f2bf(gwh[tid]);
    }
    if (tid < 6144) {
        int n = tid >> 5, k = tid & 31;
        W0Tp[tid] = (k < 3) ? f2bf(W0[k * 192 + n]) : (unsigned short)0;
    }
    if (tid < 2048) {
        int n = tid >> 6, k = tid & 63;
        Wa1T[tid] = f2bf(Wa1[k * 32 + n]);
        Wc1T[tid] = f2bf(Wc1[k * 32 + n]);
    }
    if (tid < 16 * 32) {
        int c = tid >> 5, k = tid & 31;
        float v = 0.f;
        if (c < 6 && k < 3) {
            int h = c >> 1; const float* a = (c & 1) ? ad0 : as0;
            for (int f = 0; f < 64; ++f) v += W0[k * 192 + h * 64 + f] * a[h * 64 + f];
        }
        Wsd0[tid] = f2bf(v);
    }
    if (tid < 16 * 64) {
        int c = tid >> 6, k = tid & 63;
        float v1 = 0.f, v2 = 0.f;
        if (c < 6) {
            int h = c >> 1;
            const float* a1 = (c & 1) ? ad1 : as1;
            const float* a2 = (c & 1) ? ad2 : as2;
            for (int f = 0; f < 64; ++f) {
                v1 += W1[k * 192 + h * 64 + f] * a1[h * 64 + f];
                v2 += W2[k * 192 + h * 64 + f] * a2[h * 64 + f];
            }
        }
        Wsd1[tid] = f2bf(v1);
        Wsd2[tid] = f2bf(v2);
    }
}

// ---------------------------------------------------------------------------
// Projection (round-5 verbatim, VERIFIED). Grid 512 x 256, XCD-swizzled.
// ---------------------------------------------------------------------------
template<int KDIM, int MODE>
__global__ __launch_bounds__(256) void proj_kernel(
    const unsigned short* __restrict__ A16,
    const float* __restrict__ haccp,          // [b][1024][192]
    float* __restrict__ rsum,                 // [8192][64]
    const unsigned short* __restrict__ WT,    // [192][KDIM]
    const unsigned short* __restrict__ WsdT,  // [16][KDIM]
    unsigned short* __restrict__ VT,
    float* __restrict__ st, float* __restrict__ dt)
{
    int b     = blockIdx.x & 7;
    int nbase = (int)(blockIdx.x >> 3) << 4;
    int fg = threadIdx.x >> 6, l = threadIdx.x & 63;
    int l15 = l & 15, l4 = l >> 4;
    int row = b * 1024 + nbase + l15;
    constexpr int NK = KDIM / 32;

    bf16x8 afr[NK];
    if constexpr (MODE == 0) {
        #pragma unroll
        for (int ks = 0; ks < NK; ++ks)
            afr[ks] = *(const bf16x8*)(A16 + (size_t)row * KDIM + ks * 32 + l4 * 8);
    } else {
        float sf[2][8];
        #pragma unroll
        for (int ks = 0; ks < 2; ++ks) {
            int fb = ks * 32 + l4 * 8;
            const float* hp = haccp + (size_t)row * 192 + fb;
            float4 a0 = *(const float4*)(hp);       float4 a1 = *(const float4*)(hp + 4);
            float4 c0 = *(const float4*)(hp + 64);  float4 c1 = *(const float4*)(hp + 68);
            float4 e0 = *(const float4*)(hp + 128); float4 e1 = *(const float4*)(hp + 132);
            float m[8] = {a0.x + c0.x + e0.x, a0.y + c0.y + e0.y, a0.z + c0.z + e0.z, a0.w + c0.w + e0.w,
                          a1.x + c1.x + e1.x, a1.y + c1.y + e1.y, a1.z + c1.z + e1.z, a1.w + c1.w + e1.w};
            float r[8] = {0.f,0.f,0.f,0.f,0.f,0.f,0.f,0.f};
            if constexpr (MODE == 2) {
                const float* rp = rsum + (size_t)row * 64 + fb;
                float4 r0 = *(const float4*)(rp); float4 r1 = *(const float4*)(rp + 4);
                r[0]=r0.x; r[1]=r0.y; r[2]=r0.z; r[3]=r0.w;
                r[4]=r1.x; r[5]=r1.y; r[6]=r1.z; r[7]=r1.w;
            }
            #pragma unroll
            for (int j = 0; j < 8; ++j) {
                float v = m[j] * (1.f / 3.f);
                v = (v > 0.f) ? v : (fast_exp2(v * LOG2E) - 1.f);
                sf[ks][j] = v + r[j];
            }
        }
        __syncthreads();
        if (fg == 0) {
            #pragma unroll
            for (int ks = 0; ks < 2; ++ks) {
                float* rp = rsum + (size_t)row * 64 + ks * 32 + l4 * 8;
                *(float4*)(rp)     = make_float4(sf[ks][0], sf[ks][1], sf[ks][2], sf[ks][3]);
                *(float4*)(rp + 4) = make_float4(sf[ks][4], sf[ks][5], sf[ks][6], sf[ks][7]);
            }
        }
        #pragma unroll
        for (int ks = 0; ks < 2; ++ks) {
            union { unsigned u[4]; bf16x8 v; } uu;
            #pragma unroll
            for (int jj = 0; jj < 4; ++jj)
                uu.u[jj] = cvt_pk_bf16(sf[ks][2 * jj], sf[ks][2 * jj + 1]);
            afr[ks] = uu.v;
        }
    }

    f32x4 acc[3] = {(f32x4)0.f, (f32x4)0.f, (f32x4)0.f};
    f32x4 sdacc  = (f32x4)0.f;
    #pragma unroll
    for (int ks = 0; ks < NK; ++ks) {
        int k = ks * 32 + l4 * 8;
        #pragma unroll
        for (int t = 0; t < 3; ++t) {
            int n = (fg * 3 + t) * 16 + l15;
            bf16x8 bf = *(const bf16x8*)(WT + (size_t)n * KDIM + k);
            acc[t] = MFMA(afr[ks], bf, acc[t], 0, 0, 0);
        }
        if (fg == 0) {
            bf16x8 bsd = *(const bf16x8*)(WsdT + (size_t)l15 * KDIM + k);
            sdacc = MFMA(afr[ks], bsd, sdacc, 0, 0, 0);
        }
    }
    #pragma unroll
    for (int t = 0; t < 3; ++t) {
        int hf = (fg * 3 + t) * 16 + l15;
        size_t base = ((size_t)(b * 3 + (hf >> 6)) * 64 + (hf & 63)) * 1024 + nbase + l4 * 4;
        uint2 pk;
        pk.x = cvt_pk_bf16(acc[t][0], acc[t][1]);
        pk.y = cvt_pk_bf16(acc[t][2], acc[t][3]);
        *(uint2*)(VT + base) = pk;
    }
    if (fg == 0 && l15 < 6) {
        int h = l15 >> 1;
        float* dst = (l15 & 1) ? dt : st;
        size_t base = (size_t)(b * 3 + h) * 1024 + nbase + l4 * 4;
        #pragma unroll
        for (int r = 0; r < 4; ++r) dst[base + r] = sdacc[r];
    }
}

// ---------------------------------------------------------------------------
// Attention, 16-row tiles for 2x TLP. Grid 1536 = (b=blk&7 [XCD],
// q=blk>>3: h=q>>6, tile16=q&63). Block 256 = 4 waves; wave w covers j in
// [w*256,(w+1)*256) (8 iters), computing the full 16x64 partial (4 MFMA/iter).
// Math identical to round 5 per row (factored softmax, same j order).
// LDS ~28KB -> ~5 blocks/CU (vs 3 at 32-row), grid 1536 -> ~5 waves/SIMD.
// ---------------------------------------------------------------------------
__global__ __launch_bounds__(256) void attn_head_kernel(
    const unsigned short* __restrict__ VT,
    const float* __restrict__ st, const float* __restrict__ dt,
    const unsigned int* __restrict__ maskw,   // [1024 rows][32 words]
    float* __restrict__ hacc)                 // [b][1024][192]
{
    __shared__ float F1lds[1024];
    __shared__ float F2lds[1024];
    __shared__ unsigned int lmask[16 * 33];
    __shared__ float pO[4][16 * 68];
    __shared__ float pZ[4][16];

    int b     = blockIdx.x & 7;               // = XCD
    int q     = blockIdx.x >> 3;              // 0..191
    int h     = q >> 6;
    int bh    = b * 3 + h;
    int ibase = (q & 63) << 4;
    int w = threadIdx.x >> 6, l = threadIdx.x & 63;
    int l15 = l & 15, l4 = l >> 4;

    #pragma unroll
    for (int i = 0; i < 2; ++i) {
        int idx = threadIdx.x + i * 256;      // 0..511
        int row = idx >> 5, wd = idx & 31;
        lmask[row * 33 + wd] = maskw[(size_t)(ibase + row) * 32 + wd];
    }
    {
        int t4 = threadIdx.x * 4;
        float4 dv4 = *(const float4*)(dt + (size_t)bh * 1024 + t4);
        *(float4*)(F1lds + t4) = make_float4(
            fast_exp2(dv4.x * LOG2E), fast_exp2(dv4.y * LOG2E),
            fast_exp2(dv4.z * LOG2E), fast_exp2(dv4.w * LOG2E));
        *(float4*)(F2lds + t4) = make_float4(
            fast_exp2(dv4.x * (0.2f * LOG2E)), fast_exp2(dv4.y * (0.2f * LOG2E)),
            fast_exp2(dv4.z * (0.2f * LOG2E)), fast_exp2(dv4.w * (0.2f * LOG2E)));
    }
    __syncthreads();

    float R0 = fast_exp2(st[(size_t)bh * 1024 + ibase + l15] * (-0.8f * LOG2E));
    const unsigned short* vbase = VT + (size_t)bh * 64 * 1024;

    f32x4 acc[4];
    #pragma unroll
    for (int f4 = 0; f4 < 4; ++f4) acc[f4] = (f32x4)0.f;
    float z0 = 0.f;
    int jb = w * 256;
    int w8 = w * 8;

    auto ldstep = [&](int it, float4& F1a, float4& F1b, float4& F2a, float4& F2b,
                      bf16x8& Va, bf16x8& Vb, bf16x8& Vc, bf16x8& Vd) {
        int kk = jb + it * 32 + l4 * 8;
        F1a = *(const float4*)(F1lds + kk);
        F1b = *(const float4*)(F1lds + kk + 4);
        F2a = *(const float4*)(F2lds + kk);
        F2b = *(const float4*)(F2lds + kk + 4);
        Va = *(const bf16x8*)(vbase + (size_t)(l15)      * 1024 + kk);
        Vb = *(const bf16x8*)(vbase + (size_t)(16 + l15) * 1024 + kk);
        Vc = *(const bf16x8*)(vbase + (size_t)(32 + l15) * 1024 + kk);
        Vd = *(const bf16x8*)(vbase + (size_t)(48 + l15) * 1024 + kk);
    };
    auto cstep = [&](int it, float4 F1a, float4 F1b, float4 F2a, float4 F2b,
                     bf16x8 Va, bf16x8 Vb, bf16x8 Vc, bf16x8 Vd) {
        unsigned m0 = (lmask[l15 * 33 + w8 + it] >> (l4 * 8)) & 0xffu;
        float f1[8] = {F1a.x, F1a.y, F1a.z, F1a.w, F1b.x, F1b.y, F1b.z, F1b.w};
        float f2[8] = {F2a.x, F2a.y, F2a.z, F2a.w, F2b.x, F2b.y, F2b.z, F2b.w};
        float p0[8];
        #pragma unroll
        for (int j = 0; j < 8; ++j) {
            float a0 = fmaxf(f1[j], R0 * f2[j]);
            p0[j] = ((m0 >> j) & 1) ? a0 : 0.f;
            z0 += p0[j];
        }
        union { unsigned u[4]; bf16x8 v; } ua;
        #pragma unroll
        for (int jj = 0; jj < 4; ++jj)
            ua.u[jj] = cvt_pk_bf16(p0[2 * jj], p0[2 * jj + 1]);
        acc[0] = MFMA(ua.v, Va, acc[0], 0, 0, 0);
        acc[1] = MFMA(ua.v, Vb, acc[1], 0, 0, 0);
        acc[2] = MFMA(ua.v, Vc, acc[2], 0, 0, 0);
        acc[3] = MFMA(ua.v, Vd, acc[3], 0, 0, 0);
    };

    // 2-stage software pipeline over 8 iterations (round-5 schedule)
    float4 F1a0, F1b0, F2a0, F2b0, F1a1, F1b1, F2a1, F2b1;
    bf16x8 Va0, Vb0, Vc0, Vd0, Va1, Vb1, Vc1, Vd1;
    ldstep(0, F1a0, F1b0, F2a0, F2b0, Va0, Vb0, Vc0, Vd0);
    #pragma unroll
    for (int it = 0; it < 8; it += 2) {
        if (it + 1 < 8) ldstep(it + 1, F1a1, F1b1, F2a1, F2b1, Va1, Vb1, Vc1, Vd1);
        cstep(it, F1a0, F1b0, F2a0, F2b0, Va0, Vb0, Vc0, Vd0);
        if (it + 2 < 8) ldstep(it + 2, F1a0, F1b0, F2a0, F2b0, Va0, Vb0, Vc0, Vd0);
        if (it + 1 < 8) cstep(it + 1, F1a1, F1b1, F2a1, F2b1, Va1, Vb1, Vc1, Vd1);
    }

    z0 += __shfl_xor(z0, 16); z0 += __shfl_xor(z0, 32);
    if (l < 16) pZ[w][l] = z0;
    #pragma unroll
    for (int f4 = 0; f4 < 4; ++f4)
        #pragma unroll
        for (int r = 0; r < 4; ++r)
            pO[w][(l4 * 4 + r) * 68 + f4 * 16 + l15] = acc[f4][r];
    __syncthreads();

    int row = threadIdx.x >> 4;               // 0..15
    int fo  = (threadIdx.x & 15) * 4;         // 0..60
    float zs = pZ[0][row] + pZ[1][row] + pZ[2][row] + pZ[3][row];
    float rcp = 1.f / ((zs == 0.f) ? 1.f : zs);
    float o[4] = {0.f, 0.f, 0.f, 0.f};
    #pragma unroll
    for (int ww = 0; ww < 4; ++ww) {
        float4 a = *(const float4*)(&pO[ww][row * 68 + fo]);
        o[0] += a.x; o[1] += a.y; o[2] += a.z; o[3] += a.w;
    }
    float* op = hacc + (size_t)(b * 1024 + ibase + row) * 192 + h * 64 + fo;
    *(float4*)(op) = make_float4(o[0] * rcp, o[1] * rcp, o[2] * rcp, o[3] * rcp);
}

// ---------------------------------------------------------------------------
// GRU + heads fused (round-5 verbatim, VERIFIED). Grid 256, XCD-swizzled.
// ---------------------------------------------------------------------------
__global__ __launch_bounds__(256) void gruheads_kernel(
    const float* __restrict__ haccp, const float* __restrict__ rsum,
    const unsigned short* __restrict__ hp16,
    const unsigned short* __restrict__ wi16, const unsigned short* __restrict__ wh16,
    const float* __restrict__ bi, const float* __restrict__ bh,
    const float* __restrict__ hprev,
    const unsigned short* __restrict__ Wa1T, const unsigned short* __restrict__ Wc1T,
    const float* __restrict__ ba1, const float* __restrict__ Wa2, const float* __restrict__ ba2,
    const float* __restrict__ bc1, const float* __restrict__ Wc2, const float* __restrict__ bc2,
    float* __restrict__ hnew, float* __restrict__ probs, float* __restrict__ value)
{
    __shared__ unsigned short hnlds[32 * 72];

    int b     = blockIdx.x & 7;
    int nbase = (int)(blockIdx.x >> 3) << 5;
    int w = threadIdx.x >> 6, l = threadIdx.x & 63;
    int rh = w & 1, g = w >> 1;
    int l15 = l & 15, l4 = l >> 4;
    int rowbase = b * 1024 + nbase + rh * 16;
    int arow = rowbase + l15;

    bf16x8 ai[2];
    #pragma unroll
    for (int ks = 0; ks < 2; ++ks) {
        int fb = ks * 32 + l4 * 8;
        const float* hp = haccp + (size_t)arow * 192 + fb;
        float4 a0 = *(const float4*)(hp);       float4 a1 = *(const float4*)(hp + 4);
        float4 c0 = *(const float4*)(hp + 64);  float4 c1 = *(const float4*)(hp + 68);
        float4 e0 = *(const float4*)(hp + 128); float4 e1 = *(const float4*)(hp + 132);
        const float* rp = rsum + (size_t)arow * 64 + fb;
        float4 r0 = *(const float4*)(rp);       float4 r1 = *(const float4*)(rp + 4);
        float m[8] = {a0.x + c0.x + e0.x, a0.y + c0.y + e0.y, a0.z + c0.z + e0.z, a0.w + c0.w + e0.w,
                      a1.x + c1.x + e1.x, a1.y + c1.y + e1.y, a1.z + c1.z + e1.z, a1.w + c1.w + e1.w};
        float rr[8] = {r0.x, r0.y, r0.z, r0.w, r1.x, r1.y, r1.z, r1.w};
        float sf[8];
        #pragma unroll
        for (int j = 0; j < 8; ++j) {
            float v = m[j] * (1.f / 3.f);
            v = (v > 0.f) ? v : (fast_exp2(v * LOG2E) - 1.f);
            sf[j] = v + rr[j];
        }
        union { unsigned u[4]; bf16x8 v; } uu;
        #pragma unroll
        for (int jj = 0; jj < 4; ++jj)
            uu.u[jj] = cvt_pk_bf16(sf[2 * jj], sf[2 * jj + 1]);
        ai[ks] = uu.v;
    }

    f32x4 gi[2][3], gh[2][3];
    #pragma unroll
    for (int t = 0; t < 2; ++t)
        #pragma unroll
        for (int q = 0; q < 3; ++q) { gi[t][q] = (f32x4)0.f; gh[t][q] = (f32x4)0.f; }

    #pragma unroll
    for (int ks = 0; ks < 2; ++ks) {
        int k = ks * 32 + l4 * 8;
        bf16x8 ah = *(const bf16x8*)(hp16 + (size_t)arow * 64 + k);
        #pragma unroll
        for (int t = 0; t < 2; ++t) {
            #pragma unroll
            for (int q = 0; q < 3; ++q) {
                int n = (q * 4 + g * 2 + t) * 16 + l15;
                bf16x8 bwi = *(const bf16x8*)(wi16 + (size_t)n * 64 + k);
                bf16x8 bwh = *(const bf16x8*)(wh16 + (size_t)n * 64 + k);
                gi[t][q] = MFMA(ai[ks], bwi, gi[t][q], 0, 0, 0);
                gh[t][q] = MFMA(ah,     bwh, gh[t][q], 0, 0, 0);
            }
        }
    }
    #pragma unroll
    for (int t = 0; t < 2; ++t) {
        int c = (g * 2 + t) * 16 + l15;
        float bir = bi[c], biz = bi[64 + c], bin = bi[128 + c];
        float bhr = bh[c], bhz = bh[64 + c], bhn = bh[128 + c];
        #pragma unroll
        for (int r = 0; r < 4; ++r) {
            int rloc = rh * 16 + 4 * l4 + r;
            int row = b * 1024 + nbase + rloc;
            float rr = (gi[t][0][r] + bir) + (gh[t][0][r] + bhr);
            float zz = (gi[t][1][r] + biz) + (gh[t][1][r] + bhz);
            float rg = 1.f / (1.f + fast_exp2(-rr * LOG2E));
            float zg = 1.f / (1.f + fast_exp2(-zz * LOG2E));
            float narg = (gi[t][2][r] + bin) + rg * (gh[t][2][r] + bhn);
            narg = fminf(fmaxf(narg, -15.f), 15.f);
            float e2 = fast_exp2(2.f * narg * LOG2E);
            float ng = (e2 - 1.f) / (e2 + 1.f);
            float hp = hprev[(size_t)row * 64 + c];
            float hv = (1.f - zg) * ng + zg * hp;
            hnew[(size_t)row * 64 + c] = hv;
            hnlds[rloc * 72 + c] = f2bf(hv);
        }
    }
    __syncthreads();

    const unsigned short* WT = g ? Wc1T : Wa1T;
    f32x4 acc[2] = {(f32x4)0.f, (f32x4)0.f};
    #pragma unroll
    for (int ks = 0; ks < 2; ++ks) {
        int k = ks * 32 + l4 * 8;
        bf16x8 a = *(const bf16x8*)(&hnlds[(rh * 16 + l15) * 72 + k]);
        #pragma unroll
        for (int t = 0; t < 2; ++t) {
            bf16x8 bf = *(const bf16x8*)(WT + (size_t)(t * 16 + l15) * 64 + k);
            acc[t] = MFMA(a, bf, acc[t], 0, 0, 0);
        }
    }
    int rowbase2 = b * 1024 + nbase + rh * 16;
    if (g == 0) {
        float p0[4] = {0.f,0.f,0.f,0.f}, p1[4] = {0.f,0.f,0.f,0.f};
        #pragma unroll
        for (int t = 0; t < 2; ++t) {
            int c = t * 16 + l15;
            float b1 = ba1[c], w20 = Wa2[c * 2], w21 = Wa2[c * 2 + 1];
            #pragma unroll
            for (int r = 0; r < 4; ++r) {
                float v = fmaxf(acc[t][r] + b1, 0.f);
                p0[r] += v * w20; p1[r] += v * w21;
            }
        }
        #pragma unroll
        for (int r = 0; r < 4; ++r) {
            #pragma unroll
            for (int off = 1; off < 16; off <<= 1) {
                p0[r] += __shfl_xor(p0[r], off);
                p1[r] += __shfl_xor(p1[r], off);
            }
            float l0 = p0[r] + ba2[0], l1 = p1[r] + ba2[1];
            float mm = fmaxf(l0, l1);
            float e0 = fast_exp2((l0 - mm) * LOG2E);
            float e1 = fast_exp2((l1 - mm) * LOG2E);
            float s = 1.f / (e0 + e1);
            if (l15 == 0) {
                int row = rowbase2 + 4 * l4 + r;
                probs[(size_t)row * 2]     = e0 * s;
                probs[(size_t)row * 2 + 1] = e1 * s;
            }
        }
    } else {
        float pv[4] = {0.f,0.f,0.f,0.f};
        #pragma unroll
        for (int t = 0; t < 2; ++t) {
            int c = t * 16 + l15;
            float b1 = bc1[c], w2 = Wc2[c];
            #pragma unroll
            for (int r = 0; r < 4; ++r) {
                float v = fmaxf(acc[t][r] + b1, 0.f);
                pv[r] += v * w2;
            }
        }
        #pragma unroll
        for (int r = 0; r < 4; ++r) {
            #pragma unroll
            for (int off = 1; off < 16; off <<= 1) pv[r] += __shfl_xor(pv[r], off);
            if (l15 == 0) {
                int row = rowbase2 + 4 * l4 + r;
                value[row] = pv[r] + bc2[0];
            }
        }
    }
}

// ---------------------------------------------------------------------------
extern "C" void kernel_launch(void* const* d_in, const int* in_sizes, int n_in,
                              void* d_out, int out_size, void* d_ws, size_t ws_size,
                              hipStream_t stream)
{
    const float* x      = (const float*)d_in[0];
    const int*   adj    = (const int*)d_in[1];
    const float* h_prev = (const float*)d_in[2];
    const float* W0  = (const float*)d_in[3];
    const float* as0 = (const float*)d_in[4];
    const float* ad0 = (const float*)d_in[5];
    const float* W1  = (const float*)d_in[6];
    const float* as1 = (const float*)d_in[7];
    const float* ad1 = (const float*)d_in[8];
    const float* W2  = (const float*)d_in[9];
    const float* as2 = (const float*)d_in[10];
    const float* ad2 = (const float*)d_in[11];
    const float* gwi = (const float*)d_in[12];
    const float* gwh = (const float*)d_in[13];
    const float* gbi = (const float*)d_in[14];
    const float* gbh = (const float*)d_in[15];
    const float* Wa1 = (const float*)d_in[16];
    const float* ba1 = (const float*)d_in[17];
    const float* Wa2 = (const float*)d_in[18];
    const float* ba2 = (const float*)d_in[19];
    const float* Wc1 = (const float*)d_in[20];
    const float* bc1 = (const float*)d_in[21];
    const float* Wc2 = (const float*)d_in[22];
    const float* bc2 = (const float*)d_in[23];

    float* out   = (float*)d_out;
    float* probs = out;            // (8,1024,2)
    float* value = out + 16384;    // (8,1024,1)
    float* hnew  = out + 24576;    // (8,1024,64)

    char* p = (char*)d_ws;
    auto alloc = [&](size_t bytes) { char* q = p; p += (bytes + 255) & ~(size_t)255; return q; };
    auto* maskb = (unsigned long long*)alloc(16384 * 8);
    auto*  xpad  = (unsigned short*)alloc((size_t)NROWS * 32 * 2);
    auto*  hp16  = (unsigned short*)alloc((size_t)NROWS * 64 * 2);
    auto*  VT    = (unsigned short*)alloc((size_t)8 * 3 * 64 * 1024 * 2);
    float* st    = (float*)alloc((size_t)24576 * 4);
    float* dt    = (float*)alloc((size_t)24576 * 4);
    float* hacc  = (float*)alloc((size_t)8 * 1024 * 192 * 4);
    float* rsum  = (float*)alloc((size_t)NROWS * 64 * 4);
    auto*  W0Tp  = (unsigned short*)alloc(192 * 32 * 2);
    auto*  W1T   = (unsigned short*)alloc(192 * 64 * 2);
    auto*  W2T   = (unsigned short*)alloc(192 * 64 * 2);
    auto*  wi16  = (unsigned short*)alloc(192 * 64 * 2);
    auto*  wh16  = (unsigned short*)alloc(192 * 64 * 2);
    auto*  Wa1T  = (unsigned short*)alloc(32 * 64 * 2);
    auto*  Wc1T  = (unsigned short*)alloc(32 * 64 * 2);
    auto*  Wsd0  = (unsigned short*)alloc(16 * 32 * 2);
    auto*  Wsd1  = (unsigned short*)alloc(16 * 64 * 2);
    auto*  Wsd2  = (unsigned short*)alloc(16 * 64 * 2);
    (void)ws_size; (void)in_sizes; (void)n_in; (void)out_size;

    const unsigned int* maskw = (const unsigned int*)maskb;

    setup_kernel<<<1024, 256, 0, stream>>>(
        x, adj, h_prev, W0, as0, ad0, W1, as1, ad1, W2, as2, ad2,
        gwi, gwh, Wa1, Wc1,
        maskb, xpad, hp16, W0Tp, W1T, W2T, wi16, wh16, Wa1T, Wc1T,
        Wsd0, Wsd1, Wsd2);

    // Layer 0
    proj_kernel<32, 0><<<512, 256, 0, stream>>>(xpad, nullptr, nullptr, W0Tp, Wsd0, VT, st, dt);
    attn_head_kernel<<<1536, 256, 0, stream>>>(VT, st, dt, maskw, hacc);
    // Layer 1
    proj_kernel<64, 1><<<512, 256, 0, stream>>>(nullptr, hacc, rsum, W1T, Wsd1, VT, st, dt);
    attn_head_kernel<<<1536, 256, 0, stream>>>(VT, st, dt, maskw, hacc);
    // Layer 2
    proj_kernel<64, 2><<<512, 256, 0, stream>>>(nullptr, hacc, rsum, W2T, Wsd2, VT, st, dt);
    attn_head_kernel<<<1536, 256, 0, stream>>>(VT, st, dt, maskw, hacc);
    // GRU + heads
    gruheads_kernel<<<256, 256, 0, stream>>>(
        hacc, rsum, hp16, wi16, wh16, gbi, gbh, h_prev,
        Wa1T, Wc1T, ba1, Wa2, ba2, bc1, Wc2, bc2, hnew, probs, value);
}

// Round 13
// 66.453 us; speedup vs baseline: 6.0468x; 1.6939x over previous
//
#include <hip/hip_runtime.h>
#include <hip/hip_bf16.h>
#include <stdint.h>

#define LOG2E 1.44269504f
#define NROWS 8192

using bf16x8 = __attribute__((ext_vector_type(8))) short;
using f32x4  = __attribute__((ext_vector_type(4))) float;

__device__ __forceinline__ unsigned short f2bf(float f) {
    unsigned u = __float_as_uint(f);
    u += 0x7fff + ((u >> 16) & 1);          // RNE
    return (unsigned short)(u >> 16);
}
__device__ __forceinline__ unsigned cvt_pk_bf16(float lo, float hi) {
    unsigned r;
    asm("v_cvt_pk_bf16_f32 %0, %1, %2" : "=v"(r) : "v"(lo), "v"(hi));
    return r;
}
__device__ __forceinline__ float fast_exp2(float x) { return __builtin_amdgcn_exp2f(x); }

#define MFMA __builtin_amdgcn_mfma_f32_16x16x32_bf16

// VTp layout: [bh][jc=0..31][f4=0..3][lane=0..63][e=0..7] bf16.
// lane = jseg*16 + n15, where jseg=(j>>3)&3, n15 = col&15, e = j&7,
// col = f4*16+n15 (within head), j = jc*32 + jseg*8 + e.
// attn's B-fragment load for (jc,f4) is then exactly base + lane*8 elements
// -> fully coalesced (1 cache line per quarter-wave instead of 16).

// ---------------------------------------------------------------------------
// Setup (round-5 verbatim, VERIFIED). Grid 1024 x 256.
// ---------------------------------------------------------------------------
__global__ __launch_bounds__(256) void setup_kernel(
    const float* __restrict__ x, const int* __restrict__ adj, const float* __restrict__ h_prev,
    const float* __restrict__ W0, const float* __restrict__ as0, const float* __restrict__ ad0,
    const float* __restrict__ W1, const float* __restrict__ as1, const float* __restrict__ ad1,
    const float* __restrict__ W2, const float* __restrict__ as2, const float* __restrict__ ad2,
    const float* __restrict__ gwi, const float* __restrict__ gwh,
    const float* __restrict__ Wa1, const float* __restrict__ Wc1,
    unsigned long long* __restrict__ maskbits, unsigned short* __restrict__ xpad,
    unsigned short* __restrict__ hp16,
    unsigned short* __restrict__ W0Tp, unsigned short* __restrict__ W1T, unsigned short* __restrict__ W2T,
    unsigned short* __restrict__ wi16, unsigned short* __restrict__ wh16,
    unsigned short* __restrict__ Wa1T, unsigned short* __restrict__ Wc1T,
    unsigned short* __restrict__ Wsd0, unsigned short* __restrict__ Wsd1, unsigned short* __restrict__ Wsd2)
{
    int tid  = blockIdx.x * 256 + threadIdx.x;   // 0 .. 262143
    int lane = threadIdx.x & 63;
    int wv   = tid >> 6;

    #pragma unroll
    for (int i = 0; i < 4; ++i) {
        int w   = wv * 4 + i;
        int row = w >> 4, wc = w & 15;
        int j   = wc * 64 + lane;
        unsigned long long m = __ballot(adj[row * 1024 + j] > 0);
        if (lane == 0) maskbits[w] = m;
    }
    {
        int n = tid >> 5, k = tid & 31;
        xpad[tid] = (k < 3) ? f2bf(x[n * 3 + k]) : (unsigned short)0;
    }
    hp16[tid]          = f2bf(h_prev[tid]);
    hp16[tid + 262144] = f2bf(h_prev[tid + 262144]);
    if (tid < 12288) {
        int n = tid >> 6, k = tid & 63;
        W1T[tid]  = f2bf(W1[k * 192 + n]);
        W2T[tid]  = f2bf(W2[k * 192 + n]);
        wi16[tid] = f2bf(gwi[tid]);
        wh16[tid] = f2bf(gwh[tid]);
    }
    if (tid < 6144) {
        int n = tid >> 5, k = tid & 31;
        W0Tp[tid] = (k < 3) ? f2bf(W0[k * 192 + n]) : (unsigned short)0;
    }
    if (tid < 2048) {
        int n = tid >> 6, k = tid & 63;
        Wa1T[tid] = f2bf(Wa1[k * 32 + n]);
        Wc1T[tid] = f2bf(Wc1[k * 32 + n]);
    }
    if (tid < 16 * 32) {
        int c = tid >> 5, k = tid & 31;
        float v = 0.f;
        if (c < 6 && k < 3) {
            int h = c >> 1; const float* a = (c & 1) ? ad0 : as0;
            for (int f = 0; f < 64; ++f) v += W0[k * 192 + h * 64 + f] * a[h * 64 + f];
        }
        Wsd0[tid] = f2bf(v);
    }
    if (tid < 16 * 64) {
        int c = tid >> 6, k = tid & 63;
        float v1 = 0.f, v2 = 0.f;
        if (c < 6) {
            int h = c >> 1;
            const float* a1 = (c & 1) ? ad1 : as1;
            const float* a2 = (c & 1) ? ad2 : as2;
            for (int f = 0; f < 64; ++f) {
                v1 += W1[k * 192 + h * 64 + f] * a1[h * 64 + f];
                v2 += W2[k * 192 + h * 64 + f] * a2[h * 64 + f];
            }
        }
        Wsd1[tid] = f2bf(v1);
        Wsd2[tid] = f2bf(v2);
    }
}

// ---------------------------------------------------------------------------
// Projection (round-5 math; VT store re-addressed to fragment order VTp).
// Grid 512 x 256, XCD-swizzled.
// ---------------------------------------------------------------------------
template<int KDIM, int MODE>
__global__ __launch_bounds__(256) void proj_kernel(
    const unsigned short* __restrict__ A16,
    const float* __restrict__ haccp,          // [b][1024][192]
    float* __restrict__ rsum,                 // [8192][64]
    const unsigned short* __restrict__ WT,    // [192][KDIM]
    const unsigned short* __restrict__ WsdT,  // [16][KDIM]
    unsigned short* __restrict__ VTp,         // [24][32][4][64][8]
    float* __restrict__ st, float* __restrict__ dt)
{
    int b     = blockIdx.x & 7;
    int nbase = (int)(blockIdx.x >> 3) << 4;
    int fg = threadIdx.x >> 6, l = threadIdx.x & 63;
    int l15 = l & 15, l4 = l >> 4;
    int row = b * 1024 + nbase + l15;
    constexpr int NK = KDIM / 32;

    bf16x8 afr[NK];
    if constexpr (MODE == 0) {
        #pragma unroll
        for (int ks = 0; ks < NK; ++ks)
            afr[ks] = *(const bf16x8*)(A16 + (size_t)row * KDIM + ks * 32 + l4 * 8);
    } else {
        float sf[2][8];
        #pragma unroll
        for (int ks = 0; ks < 2; ++ks) {
            int fb = ks * 32 + l4 * 8;
            const float* hp = haccp + (size_t)row * 192 + fb;
            float4 a0 = *(const float4*)(hp);       float4 a1 = *(const float4*)(hp + 4);
            float4 c0 = *(const float4*)(hp + 64);  float4 c1 = *(const float4*)(hp + 68);
            float4 e0 = *(const float4*)(hp + 128); float4 e1 = *(const float4*)(hp + 132);
            float m[8] = {a0.x + c0.x + e0.x, a0.y + c0.y + e0.y, a0.z + c0.z + e0.z, a0.w + c0.w + e0.w,
                          a1.x + c1.x + e1.x, a1.y + c1.y + e1.y, a1.z + c1.z + e1.z, a1.w + c1.w + e1.w};
            float r[8] = {0.f,0.f,0.f,0.f,0.f,0.f,0.f,0.f};
            if constexpr (MODE == 2) {
                const float* rp = rsum + (size_t)row * 64 + fb;
                float4 r0 = *(const float4*)(rp); float4 r1 = *(const float4*)(rp + 4);
                r[0]=r0.x; r[1]=r0.y; r[2]=r0.z; r[3]=r0.w;
                r[4]=r1.x; r[5]=r1.y; r[6]=r1.z; r[7]=r1.w;
            }
            #pragma unroll
            for (int j = 0; j < 8; ++j) {
                float v = m[j] * (1.f / 3.f);
                v = (v > 0.f) ? v : (fast_exp2(v * LOG2E) - 1.f);
                sf[ks][j] = v + r[j];
            }
        }
        __syncthreads();
        if (fg == 0) {
            #pragma unroll
            for (int ks = 0; ks < 2; ++ks) {
                float* rp = rsum + (size_t)row * 64 + ks * 32 + l4 * 8;
                *(float4*)(rp)     = make_float4(sf[ks][0], sf[ks][1], sf[ks][2], sf[ks][3]);
                *(float4*)(rp + 4) = make_float4(sf[ks][4], sf[ks][5], sf[ks][6], sf[ks][7]);
            }
        }
        #pragma unroll
        for (int ks = 0; ks < 2; ++ks) {
            union { unsigned u[4]; bf16x8 v; } uu;
            #pragma unroll
            for (int jj = 0; jj < 4; ++jj)
                uu.u[jj] = cvt_pk_bf16(sf[ks][2 * jj], sf[ks][2 * jj + 1]);
            afr[ks] = uu.v;
        }
    }

    f32x4 acc[3] = {(f32x4)0.f, (f32x4)0.f, (f32x4)0.f};
    f32x4 sdacc  = (f32x4)0.f;
    #pragma unroll
    for (int ks = 0; ks < NK; ++ks) {
        int k = ks * 32 + l4 * 8;
        #pragma unroll
        for (int t = 0; t < 3; ++t) {
            int n = (fg * 3 + t) * 16 + l15;
            bf16x8 bf = *(const bf16x8*)(WT + (size_t)n * KDIM + k);
            acc[t] = MFMA(afr[ks], bf, acc[t], 0, 0, 0);
        }
        if (fg == 0) {
            bf16x8 bsd = *(const bf16x8*)(WsdT + (size_t)l15 * KDIM + k);
            sdacc = MFMA(afr[ks], bsd, sdacc, 0, 0, 0);
        }
    }
    // ---- fragment-order VT store ----
    // acc[t][r] is element (j = nbase + l4*4 + r, col hf). In VTp:
    // jc = nbase>>5, jseg = ((nbase>>4)&1)*2 + (l4>>1), e0 = (l4&1)*4 (+r).
    {
        int jc   = nbase >> 5;
        int jseg = (((nbase >> 4) & 1) << 1) + (l4 >> 1);
        int e0   = (l4 & 1) * 4;
        #pragma unroll
        for (int t = 0; t < 3; ++t) {
            int hf  = (fg * 3 + t) * 16 + l15;
            int bhh = b * 3 + (hf >> 6);
            int f4h = (hf >> 4) & 3;
            size_t base = ((((size_t)(bhh * 32 + jc) * 4 + f4h) * 64
                            + (jseg * 16 + l15)) * 8 + e0);
            uint2 pk;
            pk.x = cvt_pk_bf16(acc[t][0], acc[t][1]);
            pk.y = cvt_pk_bf16(acc[t][2], acc[t][3]);
            *(uint2*)(VTp + base) = pk;
        }
    }
    if (fg == 0 && l15 < 6) {
        int h = l15 >> 1;
        float* dst = (l15 & 1) ? dt : st;
        size_t base = (size_t)(b * 3 + h) * 1024 + nbase + l4 * 4;
        #pragma unroll
        for (int r = 0; r < 4; ++r) dst[base + r] = sdacc[r];
    }
}

// ---------------------------------------------------------------------------
// Attention (round-5 structure verbatim; VT reads now coalesced via VTp).
// Grid 768 XCD-swizzled; block 256 = 4 waves; wave w covers 256 j (8 iters).
// ---------------------------------------------------------------------------
__global__ __launch_bounds__(256) void attn_head_kernel(
    const unsigned short* __restrict__ VTp,
    const float* __restrict__ st, const float* __restrict__ dt,
    const unsigned int* __restrict__ maskw,   // [1024 rows][32 words]
    float* __restrict__ hacc)                 // [b][1024][192]
{
    __shared__ float F1lds[1024];
    __shared__ float F2lds[1024];
    __shared__ unsigned int lmask[32 * 33];
    __shared__ float pO[4][32 * 68];
    __shared__ float pZ[4][32];

    int b     = blockIdx.x & 7;               // = XCD
    int q     = blockIdx.x >> 3;              // 0..95
    int h     = q >> 5;
    int bh    = b * 3 + h;
    int ibase = (q & 31) << 5;
    int w = threadIdx.x >> 6, l = threadIdx.x & 63;
    int l15 = l & 15, l4 = l >> 4;

    #pragma unroll
    for (int i = 0; i < 4; ++i) {
        int idx = threadIdx.x + i * 256;
        int row = idx >> 5, wd = idx & 31;
        lmask[row * 33 + wd] = maskw[(size_t)(ibase + row) * 32 + wd];
    }
    {
        int t4 = threadIdx.x * 4;
        float4 dv4 = *(const float4*)(dt + (size_t)bh * 1024 + t4);
        *(float4*)(F1lds + t4) = make_float4(
            fast_exp2(dv4.x * LOG2E), fast_exp2(dv4.y * LOG2E),
            fast_exp2(dv4.z * LOG2E), fast_exp2(dv4.w * LOG2E));
        *(float4*)(F2lds + t4) = make_float4(
            fast_exp2(dv4.x * (0.2f * LOG2E)), fast_exp2(dv4.y * (0.2f * LOG2E)),
            fast_exp2(dv4.z * (0.2f * LOG2E)), fast_exp2(dv4.w * (0.2f * LOG2E)));
    }
    __syncthreads();

    float R0 = fast_exp2(st[(size_t)bh * 1024 + ibase + l15]      * (-0.8f * LOG2E));
    float R1 = fast_exp2(st[(size_t)bh * 1024 + ibase + 16 + l15] * (-0.8f * LOG2E));
    const unsigned short* vbase = VTp + (size_t)bh * 32 * 4 * 64 * 8;  // 65536 el/bh

    f32x4 acc[2][4];
    #pragma unroll
    for (int rg = 0; rg < 2; ++rg)
        #pragma unroll
        for (int f4 = 0; f4 < 4; ++f4) acc[rg][f4] = (f32x4)0.f;
    float z0 = 0.f, z1 = 0.f;
    int jb = w * 256;
    int w8 = w * 8;

    auto ldstep = [&](int it, float4& F1a, float4& F1b, float4& F2a, float4& F2b,
                      bf16x8& Va, bf16x8& Vb, bf16x8& Vc, bf16x8& Vd) {
        int kk = jb + it * 32 + l4 * 8;
        F1a = *(const float4*)(F1lds + kk);
        F1b = *(const float4*)(F1lds + kk + 4);
        F2a = *(const float4*)(F2lds + kk);
        F2b = *(const float4*)(F2lds + kk + 4);
        const unsigned short* vb = vbase + (size_t)(w8 + it) * 2048 + l * 8;
        Va = *(const bf16x8*)(vb);
        Vb = *(const bf16x8*)(vb + 512);
        Vc = *(const bf16x8*)(vb + 1024);
        Vd = *(const bf16x8*)(vb + 1536);
    };
    auto cstep = [&](int it, float4 F1a, float4 F1b, float4 F2a, float4 F2b,
                     bf16x8 Va, bf16x8 Vb, bf16x8 Vc, bf16x8 Vd) {
        unsigned m0 = (lmask[l15 * 33 + w8 + it]        >> (l4 * 8)) & 0xffu;
        unsigned m1 = (lmask[(16 + l15) * 33 + w8 + it] >> (l4 * 8)) & 0xffu;
        float f1[8] = {F1a.x, F1a.y, F1a.z, F1a.w, F1b.x, F1b.y, F1b.z, F1b.w};
        float f2[8] = {F2a.x, F2a.y, F2a.z, F2a.w, F2b.x, F2b.y, F2b.z, F2b.w};
        float p0[8], p1[8];
        #pragma unroll
        for (int j = 0; j < 8; ++j) {
            float a0 = fmaxf(f1[j], R0 * f2[j]);
            p0[j] = ((m0 >> j) & 1) ? a0 : 0.f;
            z0 += p0[j];
            float a1 = fmaxf(f1[j], R1 * f2[j]);
            p1[j] = ((m1 >> j) & 1) ? a1 : 0.f;
            z1 += p1[j];
        }
        union { unsigned u[4]; bf16x8 v; } ua, ub;
        #pragma unroll
        for (int jj = 0; jj < 4; ++jj) {
            ua.u[jj] = cvt_pk_bf16(p0[2 * jj], p0[2 * jj + 1]);
            ub.u[jj] = cvt_pk_bf16(p1[2 * jj], p1[2 * jj + 1]);
        }
        acc[0][0] = MFMA(ua.v, Va, acc[0][0], 0, 0, 0);
        acc[0][1] = MFMA(ua.v, Vb, acc[0][1], 0, 0, 0);
        acc[0][2] = MFMA(ua.v, Vc, acc[0][2], 0, 0, 0);
        acc[0][3] = MFMA(ua.v, Vd, acc[0][3], 0, 0, 0);
        acc[1][0] = MFMA(ub.v, Va, acc[1][0], 0, 0, 0);
        acc[1][1] = MFMA(ub.v, Vb, acc[1][1], 0, 0, 0);
        acc[1][2] = MFMA(ub.v, Vc, acc[1][2], 0, 0, 0);
        acc[1][3] = MFMA(ub.v, Vd, acc[1][3], 0, 0, 0);
    };

    float4 F1a0, F1b0, F2a0, F2b0, F1a1, F1b1, F2a1, F2b1;
    bf16x8 Va0, Vb0, Vc0, Vd0, Va1, Vb1, Vc1, Vd1;
    ldstep(0, F1a0, F1b0, F2a0, F2b0, Va0, Vb0, Vc0, Vd0);
    #pragma unroll
    for (int it = 0; it < 8; it += 2) {
        if (it + 1 < 8) ldstep(it + 1, F1a1, F1b1, F2a1, F2b1, Va1, Vb1, Vc1, Vd1);
        cstep(it, F1a0, F1b0, F2a0, F2b0, Va0, Vb0, Vc0, Vd0);
        if (it + 2 < 8) ldstep(it + 2, F1a0, F1b0, F2a0, F2b0, Va0, Vb0, Vc0, Vd0);
        if (it + 1 < 8) cstep(it + 1, F1a1, F1b1, F2a1, F2b1, Va1, Vb1, Vc1, Vd1);
    }

    z0 += __shfl_xor(z0, 16); z0 += __shfl_xor(z0, 32);
    z1 += __shfl_xor(z1, 16); z1 += __shfl_xor(z1, 32);
    if (l4 == 0) pZ[w][l15] = z0;
    if (l4 == 1) pZ[w][16 + l15] = z1;
    #pragma unroll
    for (int rg = 0; rg < 2; ++rg)
        #pragma unroll
        for (int f4 = 0; f4 < 4; ++f4)
            #pragma unroll
            for (int r = 0; r < 4; ++r)
                pO[w][(rg * 16 + l4 * 4 + r) * 68 + f4 * 16 + l15] = acc[rg][f4][r];
    __syncthreads();

    int row = threadIdx.x >> 3;
    int fo  = (threadIdx.x & 7) * 8;
    float zs = pZ[0][row] + pZ[1][row] + pZ[2][row] + pZ[3][row];
    float rcp = 1.f / ((zs == 0.f) ? 1.f : zs);
    float o[8] = {0.f,0.f,0.f,0.f,0.f,0.f,0.f,0.f};
    #pragma unroll
    for (int ww = 0; ww < 4; ++ww) {
        const float* pp = &pO[ww][row * 68 + fo];
        float4 a = *(const float4*)(pp);
        float4 c = *(const float4*)(pp + 4);
        o[0] += a.x; o[1] += a.y; o[2] += a.z; o[3] += a.w;
        o[4] += c.x; o[5] += c.y; o[6] += c.z; o[7] += c.w;
    }
    float* op = hacc + (size_t)(b * 1024 + ibase + row) * 192 + h * 64 + fo;
    *(float4*)(op)     = make_float4(o[0] * rcp, o[1] * rcp, o[2] * rcp, o[3] * rcp);
    *(float4*)(op + 4) = make_float4(o[4] * rcp, o[5] * rcp, o[6] * rcp, o[7] * rcp);
}

// ---------------------------------------------------------------------------
// GRU + heads fused (round-5 verbatim, VERIFIED). Grid 256, XCD-swizzled.
// ---------------------------------------------------------------------------
__global__ __launch_bounds__(256) void gruheads_kernel(
    const float* __restrict__ haccp, const float* __restrict__ rsum,
    const unsigned short* __restrict__ hp16,
    const unsigned short* __restrict__ wi16, const unsigned short* __restrict__ wh16,
    const float* __restrict__ bi, const float* __restrict__ bh,
    const float* __restrict__ hprev,
    const unsigned short* __restrict__ Wa1T, const unsigned short* __restrict__ Wc1T,
    const float* __restrict__ ba1, const float* __restrict__ Wa2, const float* __restrict__ ba2,
    const float* __restrict__ bc1, const float* __restrict__ Wc2, const float* __restrict__ bc2,
    float* __restrict__ hnew, float* __restrict__ probs, float* __restrict__ value)
{
    __shared__ unsigned short hnlds[32 * 72];

    int b     = blockIdx.x & 7;
    int nbase = (int)(blockIdx.x >> 3) << 5;
    int w = threadIdx.x >> 6, l = threadIdx.x & 63;
    int rh = w & 1, g = w >> 1;
    int l15 = l & 15, l4 = l >> 4;
    int rowbase = b * 1024 + nbase + rh * 16;
    int arow = rowbase + l15;

    bf16x8 ai[2];
    #pragma unroll
    for (int ks = 0; ks < 2; ++ks) {
        int fb = ks * 32 + l4 * 8;
        const float* hp = haccp + (size_t)arow * 192 + fb;
        float4 a0 = *(const float4*)(hp);       float4 a1 = *(const float4*)(hp + 4);
        float4 c0 = *(const float4*)(hp + 64);  float4 c1 = *(const float4*)(hp + 68);
        float4 e0 = *(const float4*)(hp + 128); float4 e1 = *(const float4*)(hp + 132);
        const float* rp = rsum + (size_t)arow * 64 + fb;
        float4 r0 = *(const float4*)(rp);       float4 r1 = *(const float4*)(rp + 4);
        float m[8] = {a0.x + c0.x + e0.x, a0.y + c0.y + e0.y, a0.z + c0.z + e0.z, a0.w + c0.w + e0.w,
                      a1.x + c1.x + e1.x, a1.y + c1.y + e1.y, a1.z + c1.z + e1.z, a1.w + c1.w + e1.w};
        float rr[8] = {r0.x, r0.y, r0.z, r0.w, r1.x, r1.y, r1.z, r1.w};
        float sf[8];
        #pragma unroll
        for (int j = 0; j < 8; ++j) {
            float v = m[j] * (1.f / 3.f);
            v = (v > 0.f) ? v : (fast_exp2(v * LOG2E) - 1.f);
            sf[j] = v + rr[j];
        }
        union { unsigned u[4]; bf16x8 v; } uu;
        #pragma unroll
        for (int jj = 0; jj < 4; ++jj)
            uu.u[jj] = cvt_pk_bf16(sf[2 * jj], sf[2 * jj + 1]);
        ai[ks] = uu.v;
    }

    f32x4 gi[2][3], gh[2][3];
    #pragma unroll
    for (int t = 0; t < 2; ++t)
        #pragma unroll
        for (int q = 0; q < 3; ++q) { gi[t][q] = (f32x4)0.f; gh[t][q] = (f32x4)0.f; }

    #pragma unroll
    for (int ks = 0; ks < 2; ++ks) {
        int k = ks * 32 + l4 * 8;
        bf16x8 ah = *(const bf16x8*)(hp16 + (size_t)arow * 64 + k);
        #pragma unroll
        for (int t = 0; t < 2; ++t) {
            #pragma unroll
            for (int q = 0; q < 3; ++q) {
                int n = (q * 4 + g * 2 + t) * 16 + l15;
                bf16x8 bwi = *(const bf16x8*)(wi16 + (size_t)n * 64 + k);
                bf16x8 bwh = *(const bf16x8*)(wh16 + (size_t)n * 64 + k);
                gi[t][q] = MFMA(ai[ks], bwi, gi[t][q], 0, 0, 0);
                gh[t][q] = MFMA(ah,     bwh, gh[t][q], 0, 0, 0);
            }
        }
    }
    #pragma unroll
    for (int t = 0; t < 2; ++t) {
        int c = (g * 2 + t) * 16 + l15;
        float bir = bi[c], biz = bi[64 + c], bin = bi[128 + c];
        float bhr = bh[c], bhz = bh[64 + c], bhn = bh[128 + c];
        #pragma unroll
        for (int r = 0; r < 4; ++r) {
            int rloc = rh * 16 + 4 * l4 + r;
            int row = b * 1024 + nbase + rloc;
            float rr = (gi[t][0][r] + bir) + (gh[t][0][r] + bhr);
            float zz = (gi[t][1][r] + biz) + (gh[t][1][r] + bhz);
            float rg = 1.f / (1.f + fast_exp2(-rr * LOG2E));
            float zg = 1.f / (1.f + fast_exp2(-zz * LOG2E));
            float narg = (gi[t][2][r] + bin) + rg * (gh[t][2][r] + bhn);
            narg = fminf(fmaxf(narg, -15.f), 15.f);
            float e2 = fast_exp2(2.f * narg * LOG2E);
            float ng = (e2 - 1.f) / (e2 + 1.f);
            float hp = hprev[(size_t)row * 64 + c];
            float hv = (1.f - zg) * ng + zg * hp;
            hnew[(size_t)row * 64 + c] = hv;
            hnlds[rloc * 72 + c] = f2bf(hv);
        }
    }
    __syncthreads();

    const unsigned short* WT = g ? Wc1T : Wa1T;
    f32x4 acc[2] = {(f32x4)0.f, (f32x4)0.f};
    #pragma unroll
    for (int ks = 0; ks < 2; ++ks) {
        int k = ks * 32 + l4 * 8;
        bf16x8 a = *(const bf16x8*)(&hnlds[(rh * 16 + l15) * 72 + k]);
        #pragma unroll
        for (int t = 0; t < 2; ++t) {
            bf16x8 bf = *(const bf16x8*)(WT + (size_t)(t * 16 + l15) * 64 + k);
            acc[t] = MFMA(a, bf, acc[t], 0, 0, 0);
        }
    }
    int rowbase2 = b * 1024 + nbase + rh * 16;
    if (g == 0) {
        float p0[4] = {0.f,0.f,0.f,0.f}, p1[4] = {0.f,0.f,0.f,0.f};
        #pragma unroll
        for (int t = 0; t < 2; ++t) {
            int c = t * 16 + l15;
            float b1 = ba1[c], w20 = Wa2[c * 2], w21 = Wa2[c * 2 + 1];
            #pragma unroll
            for (int r = 0; r < 4; ++r) {
                float v = fmaxf(acc[t][r] + b1, 0.f);
                p0[r] += v * w20; p1[r] += v * w21;
            }
        }
        #pragma unroll
        for (int r = 0; r < 4; ++r) {
            #pragma unroll
            for (int off = 1; off < 16; off <<= 1) {
                p0[r] += __shfl_xor(p0[r], off);
                p1[r] += __shfl_xor(p1[r], off);
            }
            float l0 = p0[r] + ba2[0], l1 = p1[r] + ba2[1];
            float mm = fmaxf(l0, l1);
            float e0 = fast_exp2((l0 - mm) * LOG2E);
            float e1 = fast_exp2((l1 - mm) * LOG2E);
            float s = 1.f / (e0 + e1);
            if (l15 == 0) {
                int row = rowbase2 + 4 * l4 + r;
                probs[(size_t)row * 2]     = e0 * s;
                probs[(size_t)row * 2 + 1] = e1 * s;
            }
        }
    } else {
        float pv[4] = {0.f,0.f,0.f,0.f};
        #pragma unroll
        for (int t = 0; t < 2; ++t) {
            int c = t * 16 + l15;
            float b1 = bc1[c], w2 = Wc2[c];
            #pragma unroll
            for (int r = 0; r < 4; ++r) {
                float v = fmaxf(acc[t][r] + b1, 0.f);
                pv[r] += v * w2;
            }
        }
        #pragma unroll
        for (int r = 0; r < 4; ++r) {
            #pragma unroll
            for (int off = 1; off < 16; off <<= 1) pv[r] += __shfl_xor(pv[r], off);
            if (l15 == 0) {
                int row = rowbase2 + 4 * l4 + r;
                value[row] = pv[r] + bc2[0];
            }
        }
    }
}

// ---------------------------------------------------------------------------
extern "C" void kernel_launch(void* const* d_in, const int* in_sizes, int n_in,
                              void* d_out, int out_size, void* d_ws, size_t ws_size,
                              hipStream_t stream)
{
    const float* x      = (const float*)d_in[0];
    const int*   adj    = (const int*)d_in[1];
    const float* h_prev = (const float*)d_in[2];
    const float* W0  = (const float*)d_in[3];
    const float* as0 = (const float*)d_in[4];
    const float* ad0 = (const float*)d_in[5];
    const float* W1  = (const float*)d_in[6];
    const float* as1 = (const float*)d_in[7];
    const float* ad1 = (const float*)d_in[8];
    const float* W2  = (const float*)d_in[9];
    const float* as2 = (const float*)d_in[10];
    const float* ad2 = (const float*)d_in[11];
    const float* gwi = (const float*)d_in[12];
    const float* gwh = (const float*)d_in[13];
    const float* gbi = (const float*)d_in[14];
    const float* gbh = (const float*)d_in[15];
    const float* Wa1 = (const float*)d_in[16];
    const float* ba1 = (const float*)d_in[17];
    const float* Wa2 = (const float*)d_in[18];
    const float* ba2 = (const float*)d_in[19];
    const float* Wc1 = (const float*)d_in[20];
    const float* bc1 = (const float*)d_in[21];
    const float* Wc2 = (const float*)d_in[22];
    const float* bc2 = (const float*)d_in[23];

    float* out   = (float*)d_out;
    float* probs = out;            // (8,1024,2)
    float* value = out + 16384;    // (8,1024,1)
    float* hnew  = out + 24576;    // (8,1024,64)

    char* p = (char*)d_ws;
    auto alloc = [&](size_t bytes) { char* q = p; p += (bytes + 255) & ~(size_t)255; return q; };
    auto* maskb = (unsigned long long*)alloc(16384 * 8);
    auto*  xpad  = (unsigned short*)alloc((size_t)NROWS * 32 * 2);
    auto*  hp16  = (unsigned short*)alloc((size_t)NROWS * 64 * 2);
    auto*  VTp   = (unsigned short*)alloc((size_t)24 * 32 * 4 * 64 * 8 * 2);
    float* st    = (float*)alloc((size_t)24576 * 4);
    float* dt    = (float*)alloc((size_t)24576 * 4);
    float* hacc  = (float*)alloc((size_t)8 * 1024 * 192 * 4);
    float* rsum  = (float*)alloc((size_t)NROWS * 64 * 4);
    auto*  W0Tp  = (unsigned short*)alloc(192 * 32 * 2);
    auto*  W1T   = (unsigned short*)alloc(192 * 64 * 2);
    auto*  W2T   = (unsigned short*)alloc(192 * 64 * 2);
    auto*  wi16  = (unsigned short*)alloc(192 * 64 * 2);
    auto*  wh16  = (unsigned short*)alloc(192 * 64 * 2);
    auto*  Wa1T  = (unsigned short*)alloc(32 * 64 * 2);
    auto*  Wc1T  = (unsigned short*)alloc(32 * 64 * 2);
    auto*  Wsd0  = (unsigned short*)alloc(16 * 32 * 2);
    auto*  Wsd1  = (unsigned short*)alloc(16 * 64 * 2);
    auto*  Wsd2  = (unsigned short*)alloc(16 * 64 * 2);
    (void)ws_size; (void)in_sizes; (void)n_in; (void)out_size;

    const unsigned int* maskw = (const unsigned int*)maskb;

    setup_kernel<<<1024, 256, 0, stream>>>(
        x, adj, h_prev, W0, as0, ad0, W1, as1, ad1, W2, as2, ad2,
        gwi, gwh, Wa1, Wc1,
        maskb, xpad, hp16, W0Tp, W1T, W2T, wi16, wh16, Wa1T, Wc1T,
        Wsd0, Wsd1, Wsd2);

    // Layer 0
    proj_kernel<32, 0><<<512, 256, 0, stream>>>(xpad, nullptr, nullptr, W0Tp, Wsd0, VTp, st, dt);
    attn_head_kernel<<<768, 256, 0, stream>>>(VTp, st, dt, maskw, hacc);
    // Layer 1
    proj_kernel<64, 1><<<512, 256, 0, stream>>>(nullptr, hacc, rsum, W1T, Wsd1, VTp, st, dt);
    attn_head_kernel<<<768, 256, 0, stream>>>(VTp, st, dt, maskw, hacc);
    // Layer 2
    proj_kernel<64, 2><<<512, 256, 0, stream>>>(nullptr, hacc, rsum, W2T, Wsd2, VTp, st, dt);
    attn_head_kernel<<<768, 256, 0, stream>>>(VTp, st, dt, maskw, hacc);
    // GRU + heads
    gruheads_kernel<<<256, 256, 0, stream>>>(
        hacc, rsum, hp16, wi16, wh16, gbi, gbh, h_prev,
        Wa1T, Wc1T, ba1, Wa2, ba2, bc1, Wc2, bc2, hnew, probs, value);
}

// Round 14
// 62.297 us; speedup vs baseline: 6.4503x; 1.0667x over previous
//
#include <hip/hip_runtime.h>
#include <hip/hip_bf16.h>
#include <stdint.h>

#define LOG2E 1.44269504f
#define NROWS 8192

using bf16x8 = __attribute__((ext_vector_type(8))) short;
using f32x4  = __attribute__((ext_vector_type(4))) float;

__device__ __forceinline__ unsigned short f2bf(float f) {
    unsigned u = __float_as_uint(f);
    u += 0x7fff + ((u >> 16) & 1);          // RNE
    return (unsigned short)(u >> 16);
}
__device__ __forceinline__ unsigned cvt_pk_bf16(float lo, float hi) {
    unsigned r;
    asm("v_cvt_pk_bf16_f32 %0, %1, %2" : "=v"(r) : "v"(lo), "v"(hi));
    return r;
}
__device__ __forceinline__ float fast_exp2(float x) { return __builtin_amdgcn_exp2f(x); }

#define MFMA __builtin_amdgcn_mfma_f32_16x16x32_bf16

// VTp layout: [bh][jc=0..31][f4=0..3][lane=0..63][e=0..7] bf16 (round-13,
// VERIFIED): attn B-fragment loads are base + lane*16B -> fully coalesced.

// ---------------------------------------------------------------------------
// Setup (round-5 verbatim, VERIFIED). Grid 1024 x 256.
// ---------------------------------------------------------------------------
__global__ __launch_bounds__(256) void setup_kernel(
    const float* __restrict__ x, const int* __restrict__ adj, const float* __restrict__ h_prev,
    const float* __restrict__ W0, const float* __restrict__ as0, const float* __restrict__ ad0,
    const float* __restrict__ W1, const float* __restrict__ as1, const float* __restrict__ ad1,
    const float* __restrict__ W2, const float* __restrict__ as2, const float* __restrict__ ad2,
    const float* __restrict__ gwi, const float* __restrict__ gwh,
    const float* __restrict__ Wa1, const float* __restrict__ Wc1,
    unsigned long long* __restrict__ maskbits, unsigned short* __restrict__ xpad,
    unsigned short* __restrict__ hp16,
    unsigned short* __restrict__ W0Tp, unsigned short* __restrict__ W1T, unsigned short* __restrict__ W2T,
    unsigned short* __restrict__ wi16, unsigned short* __restrict__ wh16,
    unsigned short* __restrict__ Wa1T, unsigned short* __restrict__ Wc1T,
    unsigned short* __restrict__ Wsd0, unsigned short* __restrict__ Wsd1, unsigned short* __restrict__ Wsd2)
{
    int tid  = blockIdx.x * 256 + threadIdx.x;   // 0 .. 262143
    int lane = threadIdx.x & 63;
    int wv   = tid >> 6;

    #pragma unroll
    for (int i = 0; i < 4; ++i) {
        int w   = wv * 4 + i;
        int row = w >> 4, wc = w & 15;
        int j   = wc * 64 + lane;
        unsigned long long m = __ballot(adj[row * 1024 + j] > 0);
        if (lane == 0) maskbits[w] = m;
    }
    {
        int n = tid >> 5, k = tid & 31;
        xpad[tid] = (k < 3) ? f2bf(x[n * 3 + k]) : (unsigned short)0;
    }
    hp16[tid]          = f2bf(h_prev[tid]);
    hp16[tid + 262144] = f2bf(h_prev[tid + 262144]);
    if (tid < 12288) {
        int n = tid >> 6, k = tid & 63;
        W1T[tid]  = f2bf(W1[k * 192 + n]);
        W2T[tid]  = f2bf(W2[k * 192 + n]);
        wi16[tid] = f2bf(gwi[tid]);
        wh16[tid] = f2bf(gwh[tid]);
    }
    if (tid < 6144) {
        int n = tid >> 5, k = tid & 31;
        W0Tp[tid] = (k < 3) ? f2bf(W0[k * 192 + n]) : (unsigned short)0;
    }
    if (tid < 2048) {
        int n = tid >> 6, k = tid & 63;
        Wa1T[tid] = f2bf(Wa1[k * 32 + n]);
        Wc1T[tid] = f2bf(Wc1[k * 32 + n]);
    }
    if (tid < 16 * 32) {
        int c = tid >> 5, k = tid & 31;
        float v = 0.f;
        if (c < 6 && k < 3) {
            int h = c >> 1; const float* a = (c & 1) ? ad0 : as0;
            for (int f = 0; f < 64; ++f) v += W0[k * 192 + h * 64 + f] * a[h * 64 + f];
        }
        Wsd0[tid] = f2bf(v);
    }
    if (tid < 16 * 64) {
        int c = tid >> 6, k = tid & 63;
        float v1 = 0.f, v2 = 0.f;
        if (c < 6) {
            int h = c >> 1;
            const float* a1 = (c & 1) ? ad1 : as1;
            const float* a2 = (c & 1) ? ad2 : as2;
            for (int f = 0; f < 64; ++f) {
                v1 += W1[k * 192 + h * 64 + f] * a1[h * 64 + f];
                v2 += W2[k * 192 + h * 64 + f] * a2[h * 64 + f];
            }
        }
        Wsd1[tid] = f2bf(v1);
        Wsd2[tid] = f2bf(v2);
    }
}

// ---------------------------------------------------------------------------
// Projection (round-13 math + VTp store; NEW: hacc/rsum staged via LDS with
// coalesced loads -> no 16-line splits on the fragment reads).
// Grid 512 x 256, XCD-swizzled.
// ---------------------------------------------------------------------------
template<int KDIM, int MODE>
__global__ __launch_bounds__(256) void proj_kernel(
    const unsigned short* __restrict__ A16,
    const float* __restrict__ haccp,          // [b][1024][192]
    float* __restrict__ rsum,                 // [8192][64]
    const unsigned short* __restrict__ WT,    // [192][KDIM]
    const unsigned short* __restrict__ WsdT,  // [16][KDIM]
    unsigned short* __restrict__ VTp,         // [24][32][4][64][8]
    float* __restrict__ st, float* __restrict__ dt)
{
    __shared__ float hlds[(MODE == 0) ? 1 : 16][(MODE == 0) ? 1 : 196];
    __shared__ float rlds[(MODE == 2) ? 16 : 1][(MODE == 2) ? 68 : 1];

    int b     = blockIdx.x & 7;
    int nbase = (int)(blockIdx.x >> 3) << 4;
    int tid = threadIdx.x;
    int fg = tid >> 6, l = tid & 63;
    int l15 = l & 15, l4 = l >> 4;
    int row = b * 1024 + nbase + l15;
    constexpr int NK = KDIM / 32;

    bf16x8 afr[NK];
    if constexpr (MODE == 0) {
        #pragma unroll
        for (int ks = 0; ks < NK; ++ks)
            afr[ks] = *(const bf16x8*)(A16 + (size_t)row * KDIM + ks * 32 + l4 * 8);
    } else {
        // ---- coalesced staging of hacc (16 rows x 192) and rsum (16 x 64) ----
        {
            const float* hb = haccp + (size_t)(b * 1024 + nbase) * 192;
            #pragma unroll
            for (int rep = 0; rep < 3; ++rep) {
                int e4 = tid + rep * 256;          // 0..767
                int r  = e4 / 48, c4 = e4 % 48;
                float4 v = *(const float4*)(hb + (size_t)r * 192 + c4 * 4);
                *(float4*)(&hlds[r][c4 * 4]) = v;
            }
            if constexpr (MODE == 2) {
                const float* rb = rsum + (size_t)(b * 1024 + nbase) * 64;
                int r = tid >> 4, c4 = tid & 15;   // 256 float4
                float4 v = *(const float4*)(rb + (size_t)r * 64 + c4 * 4);
                *(float4*)(&rlds[r][c4 * 4]) = v;
            }
        }
        __syncthreads();       // staging done; also orders rsum reads before writes

        float sf[2][8];
        #pragma unroll
        for (int ks = 0; ks < 2; ++ks) {
            int fb = ks * 32 + l4 * 8;
            float4 a0 = *(const float4*)(&hlds[l15][fb]);
            float4 a1 = *(const float4*)(&hlds[l15][fb + 4]);
            float4 c0 = *(const float4*)(&hlds[l15][64 + fb]);
            float4 c1 = *(const float4*)(&hlds[l15][64 + fb + 4]);
            float4 e0 = *(const float4*)(&hlds[l15][128 + fb]);
            float4 e1 = *(const float4*)(&hlds[l15][128 + fb + 4]);
            float m[8] = {a0.x + c0.x + e0.x, a0.y + c0.y + e0.y, a0.z + c0.z + e0.z, a0.w + c0.w + e0.w,
                          a1.x + c1.x + e1.x, a1.y + c1.y + e1.y, a1.z + c1.z + e1.z, a1.w + c1.w + e1.w};
            float r[8] = {0.f,0.f,0.f,0.f,0.f,0.f,0.f,0.f};
            if constexpr (MODE == 2) {
                float4 r0 = *(const float4*)(&rlds[l15][fb]);
                float4 r1 = *(const float4*)(&rlds[l15][fb + 4]);
                r[0]=r0.x; r[1]=r0.y; r[2]=r0.z; r[3]=r0.w;
                r[4]=r1.x; r[5]=r1.y; r[6]=r1.z; r[7]=r1.w;
            }
            #pragma unroll
            for (int j = 0; j < 8; ++j) {
                float v = m[j] * (1.f / 3.f);
                v = (v > 0.f) ? v : (fast_exp2(v * LOG2E) - 1.f);
                sf[ks][j] = v + r[j];
            }
        }
        if (fg == 0) {
            #pragma unroll
            for (int ks = 0; ks < 2; ++ks) {
                float* rp = rsum + (size_t)row * 64 + ks * 32 + l4 * 8;
                *(float4*)(rp)     = make_float4(sf[ks][0], sf[ks][1], sf[ks][2], sf[ks][3]);
                *(float4*)(rp + 4) = make_float4(sf[ks][4], sf[ks][5], sf[ks][6], sf[ks][7]);
            }
        }
        #pragma unroll
        for (int ks = 0; ks < 2; ++ks) {
            union { unsigned u[4]; bf16x8 v; } uu;
            #pragma unroll
            for (int jj = 0; jj < 4; ++jj)
                uu.u[jj] = cvt_pk_bf16(sf[ks][2 * jj], sf[ks][2 * jj + 1]);
            afr[ks] = uu.v;
        }
    }

    f32x4 acc[3] = {(f32x4)0.f, (f32x4)0.f, (f32x4)0.f};
    f32x4 sdacc  = (f32x4)0.f;
    #pragma unroll
    for (int ks = 0; ks < NK; ++ks) {
        int k = ks * 32 + l4 * 8;
        #pragma unroll
        for (int t = 0; t < 3; ++t) {
            int n = (fg * 3 + t) * 16 + l15;
            bf16x8 bf = *(const bf16x8*)(WT + (size_t)n * KDIM + k);
            acc[t] = MFMA(afr[ks], bf, acc[t], 0, 0, 0);
        }
        if (fg == 0) {
            bf16x8 bsd = *(const bf16x8*)(WsdT + (size_t)l15 * KDIM + k);
            sdacc = MFMA(afr[ks], bsd, sdacc, 0, 0, 0);
        }
    }
    // ---- fragment-order VT store (round-13, VERIFIED) ----
    {
        int jc   = nbase >> 5;
        int jseg = (((nbase >> 4) & 1) << 1) + (l4 >> 1);
        int e0   = (l4 & 1) * 4;
        #pragma unroll
        for (int t = 0; t < 3; ++t) {
            int hf  = (fg * 3 + t) * 16 + l15;
            int bhh = b * 3 + (hf >> 6);
            int f4h = (hf >> 4) & 3;
            size_t base = ((((size_t)(bhh * 32 + jc) * 4 + f4h) * 64
                            + (jseg * 16 + l15)) * 8 + e0);
            uint2 pk;
            pk.x = cvt_pk_bf16(acc[t][0], acc[t][1]);
            pk.y = cvt_pk_bf16(acc[t][2], acc[t][3]);
            *(uint2*)(VTp + base) = pk;
        }
    }
    if (fg == 0 && l15 < 6) {
        int h = l15 >> 1;
        float* dst = (l15 & 1) ? dt : st;
        size_t base = (size_t)(b * 3 + h) * 1024 + nbase + l4 * 4;
        #pragma unroll
        for (int r = 0; r < 4; ++r) dst[base + r] = sdacc[r];
    }
}

// ---------------------------------------------------------------------------
// Attention (round-13 verbatim, VERIFIED). Grid 768 XCD-swizzled.
// ---------------------------------------------------------------------------
__global__ __launch_bounds__(256) void attn_head_kernel(
    const unsigned short* __restrict__ VTp,
    const float* __restrict__ st, const float* __restrict__ dt,
    const unsigned int* __restrict__ maskw,   // [1024 rows][32 words]
    float* __restrict__ hacc)                 // [b][1024][192]
{
    __shared__ float F1lds[1024];
    __shared__ float F2lds[1024];
    __shared__ unsigned int lmask[32 * 33];
    __shared__ float pO[4][32 * 68];
    __shared__ float pZ[4][32];

    int b     = blockIdx.x & 7;               // = XCD
    int q     = blockIdx.x >> 3;              // 0..95
    int h     = q >> 5;
    int bh    = b * 3 + h;
    int ibase = (q & 31) << 5;
    int w = threadIdx.x >> 6, l = threadIdx.x & 63;
    int l15 = l & 15, l4 = l >> 4;

    #pragma unroll
    for (int i = 0; i < 4; ++i) {
        int idx = threadIdx.x + i * 256;
        int row = idx >> 5, wd = idx & 31;
        lmask[row * 33 + wd] = maskw[(size_t)(ibase + row) * 32 + wd];
    }
    {
        int t4 = threadIdx.x * 4;
        float4 dv4 = *(const float4*)(dt + (size_t)bh * 1024 + t4);
        *(float4*)(F1lds + t4) = make_float4(
            fast_exp2(dv4.x * LOG2E), fast_exp2(dv4.y * LOG2E),
            fast_exp2(dv4.z * LOG2E), fast_exp2(dv4.w * LOG2E));
        *(float4*)(F2lds + t4) = make_float4(
            fast_exp2(dv4.x * (0.2f * LOG2E)), fast_exp2(dv4.y * (0.2f * LOG2E)),
            fast_exp2(dv4.z * (0.2f * LOG2E)), fast_exp2(dv4.w * (0.2f * LOG2E)));
    }
    __syncthreads();

    float R0 = fast_exp2(st[(size_t)bh * 1024 + ibase + l15]      * (-0.8f * LOG2E));
    float R1 = fast_exp2(st[(size_t)bh * 1024 + ibase + 16 + l15] * (-0.8f * LOG2E));
    const unsigned short* vbase = VTp + (size_t)bh * 32 * 4 * 64 * 8;

    f32x4 acc[2][4];
    #pragma unroll
    for (int rg = 0; rg < 2; ++rg)
        #pragma unroll
        for (int f4 = 0; f4 < 4; ++f4) acc[rg][f4] = (f32x4)0.f;
    float z0 = 0.f, z1 = 0.f;
    int jb = w * 256;
    int w8 = w * 8;

    auto ldstep = [&](int it, float4& F1a, float4& F1b, float4& F2a, float4& F2b,
                      bf16x8& Va, bf16x8& Vb, bf16x8& Vc, bf16x8& Vd) {
        int kk = jb + it * 32 + l4 * 8;
        F1a = *(const float4*)(F1lds + kk);
        F1b = *(const float4*)(F1lds + kk + 4);
        F2a = *(const float4*)(F2lds + kk);
        F2b = *(const float4*)(F2lds + kk + 4);
        const unsigned short* vb = vbase + (size_t)(w8 + it) * 2048 + l * 8;
        Va = *(const bf16x8*)(vb);
        Vb = *(const bf16x8*)(vb + 512);
        Vc = *(const bf16x8*)(vb + 1024);
        Vd = *(const bf16x8*)(vb + 1536);
    };
    auto cstep = [&](int it, float4 F1a, float4 F1b, float4 F2a, float4 F2b,
                     bf16x8 Va, bf16x8 Vb, bf16x8 Vc, bf16x8 Vd) {
        unsigned m0 = (lmask[l15 * 33 + w8 + it]        >> (l4 * 8)) & 0xffu;
        unsigned m1 = (lmask[(16 + l15) * 33 + w8 + it] >> (l4 * 8)) & 0xffu;
        float f1[8] = {F1a.x, F1a.y, F1a.z, F1a.w, F1b.x, F1b.y, F1b.z, F1b.w};
        float f2[8] = {F2a.x, F2a.y, F2a.z, F2a.w, F2b.x, F2b.y, F2b.z, F2b.w};
        float p0[8], p1[8];
        #pragma unroll
        for (int j = 0; j < 8; ++j) {
            float a0 = fmaxf(f1[j], R0 * f2[j]);
            p0[j] = ((m0 >> j) & 1) ? a0 : 0.f;
            z0 += p0[j];
            float a1 = fmaxf(f1[j], R1 * f2[j]);
            p1[j] = ((m1 >> j) & 1) ? a1 : 0.f;
            z1 += p1[j];
        }
        union { unsigned u[4]; bf16x8 v; } ua, ub;
        #pragma unroll
        for (int jj = 0; jj < 4; ++jj) {
            ua.u[jj] = cvt_pk_bf16(p0[2 * jj], p0[2 * jj + 1]);
            ub.u[jj] = cvt_pk_bf16(p1[2 * jj], p1[2 * jj + 1]);
        }
        acc[0][0] = MFMA(ua.v, Va, acc[0][0], 0, 0, 0);
        acc[0][1] = MFMA(ua.v, Vb, acc[0][1], 0, 0, 0);
        acc[0][2] = MFMA(ua.v, Vc, acc[0][2], 0, 0, 0);
        acc[0][3] = MFMA(ua.v, Vd, acc[0][3], 0, 0, 0);
        acc[1][0] = MFMA(ub.v, Va, acc[1][0], 0, 0, 0);
        acc[1][1] = MFMA(ub.v, Vb, acc[1][1], 0, 0, 0);
        acc[1][2] = MFMA(ub.v, Vc, acc[1][2], 0, 0, 0);
        acc[1][3] = MFMA(ub.v, Vd, acc[1][3], 0, 0, 0);
    };

    float4 F1a0, F1b0, F2a0, F2b0, F1a1, F1b1, F2a1, F2b1;
    bf16x8 Va0, Vb0, Vc0, Vd0, Va1, Vb1, Vc1, Vd1;
    ldstep(0, F1a0, F1b0, F2a0, F2b0, Va0, Vb0, Vc0, Vd0);
    #pragma unroll
    for (int it = 0; it < 8; it += 2) {
        if (it + 1 < 8) ldstep(it + 1, F1a1, F1b1, F2a1, F2b1, Va1, Vb1, Vc1, Vd1);
        cstep(it, F1a0, F1b0, F2a0, F2b0, Va0, Vb0, Vc0, Vd0);
        if (it + 2 < 8) ldstep(it + 2, F1a0, F1b0, F2a0, F2b0, Va0, Vb0, Vc0, Vd0);
        if (it + 1 < 8) cstep(it + 1, F1a1, F1b1, F2a1, F2b1, Va1, Vb1, Vc1, Vd1);
    }

    z0 += __shfl_xor(z0, 16); z0 += __shfl_xor(z0, 32);
    z1 += __shfl_xor(z1, 16); z1 += __shfl_xor(z1, 32);
    if (l4 == 0) pZ[w][l15] = z0;
    if (l4 == 1) pZ[w][16 + l15] = z1;
    #pragma unroll
    for (int rg = 0; rg < 2; ++rg)
        #pragma unroll
        for (int f4 = 0; f4 < 4; ++f4)
            #pragma unroll
            for (int r = 0; r < 4; ++r)
                pO[w][(rg * 16 + l4 * 4 + r) * 68 + f4 * 16 + l15] = acc[rg][f4][r];
    __syncthreads();

    int row = threadIdx.x >> 3;
    int fo  = (threadIdx.x & 7) * 8;
    float zs = pZ[0][row] + pZ[1][row] + pZ[2][row] + pZ[3][row];
    float rcp = 1.f / ((zs == 0.f) ? 1.f : zs);
    float o[8] = {0.f,0.f,0.f,0.f,0.f,0.f,0.f,0.f};
    #pragma unroll
    for (int ww = 0; ww < 4; ++ww) {
        const float* pp = &pO[ww][row * 68 + fo];
        float4 a = *(const float4*)(pp);
        float4 c = *(const float4*)(pp + 4);
        o[0] += a.x; o[1] += a.y; o[2] += a.z; o[3] += a.w;
        o[4] += c.x; o[5] += c.y; o[6] += c.z; o[7] += c.w;
    }
    float* op = hacc + (size_t)(b * 1024 + ibase + row) * 192 + h * 64 + fo;
    *(float4*)(op)     = make_float4(o[0] * rcp, o[1] * rcp, o[2] * rcp, o[3] * rcp);
    *(float4*)(op + 4) = make_float4(o[4] * rcp, o[5] * rcp, o[6] * rcp, o[7] * rcp);
}

// ---------------------------------------------------------------------------
// GRU + heads fused (round-5 math; NEW: hacc/rsum staged via LDS coalesced).
// Grid 256, XCD-swizzled.
// ---------------------------------------------------------------------------
__global__ __launch_bounds__(256) void gruheads_kernel(
    const float* __restrict__ haccp, const float* __restrict__ rsum,
    const unsigned short* __restrict__ hp16,
    const unsigned short* __restrict__ wi16, const unsigned short* __restrict__ wh16,
    const float* __restrict__ bi, const float* __restrict__ bh,
    const float* __restrict__ hprev,
    const unsigned short* __restrict__ Wa1T, const unsigned short* __restrict__ Wc1T,
    const float* __restrict__ ba1, const float* __restrict__ Wa2, const float* __restrict__ ba2,
    const float* __restrict__ bc1, const float* __restrict__ Wc2, const float* __restrict__ bc2,
    float* __restrict__ hnew, float* __restrict__ probs, float* __restrict__ value)
{
    __shared__ float hlds[32][196];
    __shared__ float rlds[32][68];
    __shared__ unsigned short hnlds[32 * 72];

    int b     = blockIdx.x & 7;
    int nbase = (int)(blockIdx.x >> 3) << 5;
    int tid = threadIdx.x;
    int w = tid >> 6, l = tid & 63;
    int rh = w & 1, g = w >> 1;
    int l15 = l & 15, l4 = l >> 4;
    int rowbase = b * 1024 + nbase + rh * 16;
    int arow = rowbase + l15;
    int lrow = rh * 16 + l15;

    // ---- coalesced staging: hacc 32x192, rsum 32x64 ----
    {
        const float* hb = haccp + (size_t)(b * 1024 + nbase) * 192;
        #pragma unroll
        for (int rep = 0; rep < 6; ++rep) {
            int e4 = tid + rep * 256;              // 0..1535
            int r  = e4 / 48, c4 = e4 % 48;
            float4 v = *(const float4*)(hb + (size_t)r * 192 + c4 * 4);
            *(float4*)(&hlds[r][c4 * 4]) = v;
        }
        const float* rb = rsum + (size_t)(b * 1024 + nbase) * 64;
        #pragma unroll
        for (int rep = 0; rep < 2; ++rep) {
            int e4 = tid + rep * 256;              // 0..511
            int r  = e4 >> 4, c4 = e4 & 15;
            float4 v = *(const float4*)(rb + (size_t)r * 64 + c4 * 4);
            *(float4*)(&rlds[r][c4 * 4]) = v;
        }
    }
    __syncthreads();

    bf16x8 ai[2];
    #pragma unroll
    for (int ks = 0; ks < 2; ++ks) {
        int fb = ks * 32 + l4 * 8;
        float4 a0 = *(const float4*)(&hlds[lrow][fb]);
        float4 a1 = *(const float4*)(&hlds[lrow][fb + 4]);
        float4 c0 = *(const float4*)(&hlds[lrow][64 + fb]);
        float4 c1 = *(const float4*)(&hlds[lrow][64 + fb + 4]);
        float4 e0 = *(const float4*)(&hlds[lrow][128 + fb]);
        float4 e1 = *(const float4*)(&hlds[lrow][128 + fb + 4]);
        float4 r0 = *(const float4*)(&rlds[lrow][fb]);
        float4 r1 = *(const float4*)(&rlds[lrow][fb + 4]);
        float m[8] = {a0.x + c0.x + e0.x, a0.y + c0.y + e0.y, a0.z + c0.z + e0.z, a0.w + c0.w + e0.w,
                      a1.x + c1.x + e1.x, a1.y + c1.y + e1.y, a1.z + c1.z + e1.z, a1.w + c1.w + e1.w};
        float rr[8] = {r0.x, r0.y, r0.z, r0.w, r1.x, r1.y, r1.z, r1.w};
        float sf[8];
        #pragma unroll
        for (int j = 0; j < 8; ++j) {
            float v = m[j] * (1.f / 3.f);
            v = (v > 0.f) ? v : (fast_exp2(v * LOG2E) - 1.f);
            sf[j] = v + rr[j];
        }
        union { unsigned u[4]; bf16x8 v; } uu;
        #pragma unroll
        for (int jj = 0; jj < 4; ++jj)
            uu.u[jj] = cvt_pk_bf16(sf[2 * jj], sf[2 * jj + 1]);
        ai[ks] = uu.v;
    }

    f32x4 gi[2][3], gh[2][3];
    #pragma unroll
    for (int t = 0; t < 2; ++t)
        #pragma unroll
        for (int q = 0; q < 3; ++q) { gi[t][q] = (f32x4)0.f; gh[t][q] = (f32x4)0.f; }

    #pragma unroll
    for (int ks = 0; ks < 2; ++ks) {
        int k = ks * 32 + l4 * 8;
        bf16x8 ah = *(const bf16x8*)(hp16 + (size_t)arow * 64 + k);
        #pragma unroll
        for (int t = 0; t < 2; ++t) {
            #pragma unroll
            for (int q = 0; q < 3; ++q) {
                int n = (q * 4 + g * 2 + t) * 16 + l15;
                bf16x8 bwi = *(const bf16x8*)(wi16 + (size_t)n * 64 + k);
                bf16x8 bwh = *(const bf16x8*)(wh16 + (size_t)n * 64 + k);
                gi[t][q] = MFMA(ai[ks], bwi, gi[t][q], 0, 0, 0);
                gh[t][q] = MFMA(ah,     bwh, gh[t][q], 0, 0, 0);
            }
        }
    }
    #pragma unroll
    for (int t = 0; t < 2; ++t) {
        int c = (g * 2 + t) * 16 + l15;
        float bir = bi[c], biz = bi[64 + c], bin = bi[128 + c];
        float bhr = bh[c], bhz = bh[64 + c], bhn = bh[128 + c];
        #pragma unroll
        for (int r = 0; r < 4; ++r) {
            int rloc = rh * 16 + 4 * l4 + r;
            int row = b * 1024 + nbase + rloc;
            float rr = (gi[t][0][r] + bir) + (gh[t][0][r] + bhr);
            float zz = (gi[t][1][r] + biz) + (gh[t][1][r] + bhz);
            float rg = 1.f / (1.f + fast_exp2(-rr * LOG2E));
            float zg = 1.f / (1.f + fast_exp2(-zz * LOG2E));
            float narg = (gi[t][2][r] + bin) + rg * (gh[t][2][r] + bhn);
            narg = fminf(fmaxf(narg, -15.f), 15.f);
            float e2 = fast_exp2(2.f * narg * LOG2E);
            float ng = (e2 - 1.f) / (e2 + 1.f);
            float hp = hprev[(size_t)row * 64 + c];
            float hv = (1.f - zg) * ng + zg * hp;
            hnew[(size_t)row * 64 + c] = hv;
            hnlds[rloc * 72 + c] = f2bf(hv);
        }
    }
    __syncthreads();

    const unsigned short* WT = g ? Wc1T : Wa1T;
    f32x4 acc[2] = {(f32x4)0.f, (f32x4)0.f};
    #pragma unroll
    for (int ks = 0; ks < 2; ++ks) {
        int k = ks * 32 + l4 * 8;
        bf16x8 a = *(const bf16x8*)(&hnlds[(rh * 16 + l15) * 72 + k]);
        #pragma unroll
        for (int t = 0; t < 2; ++t) {
            bf16x8 bf = *(const bf16x8*)(WT + (size_t)(t * 16 + l15) * 64 + k);
            acc[t] = MFMA(a, bf, acc[t], 0, 0, 0);
        }
    }
    int rowbase2 = b * 1024 + nbase + rh * 16;
    if (g == 0) {
        float p0[4] = {0.f,0.f,0.f,0.f}, p1[4] = {0.f,0.f,0.f,0.f};
        #pragma unroll
        for (int t = 0; t < 2; ++t) {
            int c = t * 16 + l15;
            float b1 = ba1[c], w20 = Wa2[c * 2], w21 = Wa2[c * 2 + 1];
            #pragma unroll
            for (int r = 0; r < 4; ++r) {
                float v = fmaxf(acc[t][r] + b1, 0.f);
                p0[r] += v * w20; p1[r] += v * w21;
            }
        }
        #pragma unroll
        for (int r = 0; r < 4; ++r) {
            #pragma unroll
            for (int off = 1; off < 16; off <<= 1) {
                p0[r] += __shfl_xor(p0[r], off);
                p1[r] += __shfl_xor(p1[r], off);
            }
            float l0 = p0[r] + ba2[0], l1 = p1[r] + ba2[1];
            float mm = fmaxf(l0, l1);
            float e0 = fast_exp2((l0 - mm) * LOG2E);
            float e1 = fast_exp2((l1 - mm) * LOG2E);
            float s = 1.f / (e0 + e1);
            if (l15 == 0) {
                int row = rowbase2 + 4 * l4 + r;
                probs[(size_t)row * 2]     = e0 * s;
                probs[(size_t)row * 2 + 1] = e1 * s;
            }
        }
    } else {
        float pv[4] = {0.f,0.f,0.f,0.f};
        #pragma unroll
        for (int t = 0; t < 2; ++t) {
            int c = t * 16 + l15;
            float b1 = bc1[c], w2 = Wc2[c];
            #pragma unroll
            for (int r = 0; r < 4; ++r) {
                float v = fmaxf(acc[t][r] + b1, 0.f);
                pv[r] += v * w2;
            }
        }
        #pragma unroll
        for (int r = 0; r < 4; ++r) {
            #pragma unroll
            for (int off = 1; off < 16; off <<= 1) pv[r] += __shfl_xor(pv[r], off);
            if (l15 == 0) {
                int row = rowbase2 + 4 * l4 + r;
                value[row] = pv[r] + bc2[0];
            }
        }
    }
}

// ---------------------------------------------------------------------------
extern "C" void kernel_launch(void* const* d_in, const int* in_sizes, int n_in,
                              void* d_out, int out_size, void* d_ws, size_t ws_size,
                              hipStream_t stream)
{
    const float* x      = (const float*)d_in[0];
    const int*   adj    = (const int*)d_in[1];
    const float* h_prev = (const float*)d_in[2];
    const float* W0  = (const float*)d_in[3];
    const float* as0 = (const float*)d_in[4];
    const float* ad0 = (const float*)d_in[5];
    const float* W1  = (const float*)d_in[6];
    const float* as1 = (const float*)d_in[7];
    const float* ad1 = (const float*)d_in[8];
    const float* W2  = (const float*)d_in[9];
    const float* as2 = (const float*)d_in[10];
    const float* ad2 = (const float*)d_in[11];
    const float* gwi = (const float*)d_in[12];
    const float* gwh = (const float*)d_in[13];
    const float* gbi = (const float*)d_in[14];
    const float* gbh = (const float*)d_in[15];
    const float* Wa1 = (const float*)d_in[16];
    const float* ba1 = (const float*)d_in[17];
    const float* Wa2 = (const float*)d_in[18];
    const float* ba2 = (const float*)d_in[19];
    const float* Wc1 = (const float*)d_in[20];
    const float* bc1 = (const float*)d_in[21];
    const float* Wc2 = (const float*)d_in[22];
    const float* bc2 = (const float*)d_in[23];

    float* out   = (float*)d_out;
    float* probs = out;            // (8,1024,2)
    float* value = out + 16384;    // (8,1024,1)
    float* hnew  = out + 24576;    // (8,1024,64)

    char* p = (char*)d_ws;
    auto alloc = [&](size_t bytes) { char* q = p; p += (bytes + 255) & ~(size_t)255; return q; };
    auto* maskb = (unsigned long long*)alloc(16384 * 8);
    auto*  xpad  = (unsigned short*)alloc((size_t)NROWS * 32 * 2);
    auto*  hp16  = (unsigned short*)alloc((size_t)NROWS * 64 * 2);
    auto*  VTp   = (unsigned short*)alloc((size_t)24 * 32 * 4 * 64 * 8 * 2);
    float* st    = (float*)alloc((size_t)24576 * 4);
    float* dt    = (float*)alloc((size_t)24576 * 4);
    float* hacc  = (float*)alloc((size_t)8 * 1024 * 192 * 4);
    float* rsum  = (float*)alloc((size_t)NROWS * 64 * 4);
    auto*  W0Tp  = (unsigned short*)alloc(192 * 32 * 2);
    auto*  W1T   = (unsigned short*)alloc(192 * 64 * 2);
    auto*  W2T   = (unsigned short*)alloc(192 * 64 * 2);
    auto*  wi16  = (unsigned short*)alloc(192 * 64 * 2);
    auto*  wh16  = (unsigned short*)alloc(192 * 64 * 2);
    auto*  Wa1T  = (unsigned short*)alloc(32 * 64 * 2);
    auto*  Wc1T  = (unsigned short*)alloc(32 * 64 * 2);
    auto*  Wsd0  = (unsigned short*)alloc(16 * 32 * 2);
    auto*  Wsd1  = (unsigned short*)alloc(16 * 64 * 2);
    auto*  Wsd2  = (unsigned short*)alloc(16 * 64 * 2);
    (void)ws_size; (void)in_sizes; (void)n_in; (void)out_size;

    const unsigned int* maskw = (const unsigned int*)maskb;

    setup_kernel<<<1024, 256, 0, stream>>>(
        x, adj, h_prev, W0, as0, ad0, W1, as1, ad1, W2, as2, ad2,
        gwi, gwh, Wa1, Wc1,
        maskb, xpad, hp16, W0Tp, W1T, W2T, wi16, wh16, Wa1T, Wc1T,
        Wsd0, Wsd1, Wsd2);

    // Layer 0
    proj_kernel<32, 0><<<512, 256, 0, stream>>>(xpad, nullptr, nullptr, W0Tp, Wsd0, VTp, st, dt);
    attn_head_kernel<<<768, 256, 0, stream>>>(VTp, st, dt, maskw, hacc);
    // Layer 1
    proj_kernel<64, 1><<<512, 256, 0, stream>>>(nullptr, hacc, rsum, W1T, Wsd1, VTp, st, dt);
    attn_head_kernel<<<768, 256, 0, stream>>>(VTp, st, dt, maskw, hacc);
    // Layer 2
    proj_kernel<64, 2><<<512, 256, 0, stream>>>(nullptr, hacc, rsum, W2T, Wsd2, VTp, st, dt);
    attn_head_kernel<<<768, 256, 0, stream>>>(VTp, st, dt, maskw, hacc);
    // GRU + heads
    gruheads_kernel<<<256, 256, 0, stream>>>(
        hacc, rsum, hp16, wi16, wh16, gbi, gbh, h_prev,
        Wa1T, Wc1T, ba1, Wa2, ba2, bc1, Wc2, bc2, hnew, probs, value);
}